// Round 4
// baseline (437.872 us; speedup 1.0000x reference)
//
#include <hip/hip_runtime.h>
#include <math.h>

#define NN 50000
#define NE 800000
#define ET (NE + NN)          // edges + self loops
#define F1 256                // HEADS*HID
#define NEG 0.2f
#define BN_EPS 1e-5f

typedef __attribute__((ext_vector_type(8))) short short8;
typedef __attribute__((ext_vector_type(4))) float float4v;
typedef __attribute__((ext_vector_type(4))) unsigned short ushort4v;

__device__ __forceinline__ float bf2f(unsigned short u) {
    unsigned int x = ((unsigned int)u) << 16;
    return __builtin_bit_cast(float, x);
}
__device__ __forceinline__ unsigned short f2bf(float f) {
    unsigned int x = __builtin_bit_cast(unsigned int, f);
    unsigned int lsb = (x >> 16) & 1u;
    x += 0x7fffu + lsb;
    return (unsigned short)(x >> 16);
}
__device__ __forceinline__ float lrelu(float x) { return x > 0.f ? x : NEG * x; }

// ---------------- merged prep: W1 transpose, W2 transpose, BN folds ----------------
__global__ void prep_misc(const float* __restrict__ W1, unsigned short* __restrict__ W1t,
                          const float* __restrict__ W2, unsigned short* __restrict__ W2t,
                          const float* __restrict__ b1, const float* __restrict__ g1,
                          const float* __restrict__ be1, const float* __restrict__ m1,
                          const float* __restrict__ v1, float* __restrict__ S1, float* __restrict__ T1,
                          const float* __restrict__ b2, const float* __restrict__ g2,
                          const float* __restrict__ be2, const float* __restrict__ m2,
                          const float* __restrict__ v2, float* __restrict__ S2, float* __restrict__ T2) {
    int blk = blockIdx.x, tid = threadIdx.x;
    if (blk < 128) {               // W1t: [256][128] <- W1 [128][256]
        int id = blk * 256 + tid;  // id over 32768
        int n = id >> 7, k = id & 127;
        W1t[id] = f2bf(W1[k * 256 + n]);
    } else if (blk < 384) {        // W2t: [256][256] <- W2 [256][256]
        int id = (blk - 128) * 256 + tid;
        int n = id >> 8, k = id & 255;
        W2t[id] = f2bf(W2[k * 256 + n]);
    } else if (blk == 384) {
        float s = g1[tid] * rsqrtf(v1[tid] + BN_EPS);
        S1[tid] = s;
        T1[tid] = (b1[tid] - m1[tid]) * s + be1[tid];
    } else {
        float s = g2[tid] * rsqrtf(v2[tid] + BN_EPS);
        S2[tid] = s;
        T2[tid] = (b2[tid] - m2[tid]) * s + be2[tid];
    }
}

// ---------------- CSR build (rank-based, single atomic pass) ----------------
__global__ void edge_hist_rank(const int* __restrict__ ei, int* __restrict__ counts, int* __restrict__ rank) {
    int e = blockIdx.x * 256 + threadIdx.x;
    if (e < ET) {
        int dst = (e < NE) ? ei[NE + e] : (e - NE);
        rank[e] = atomicAdd(&counts[dst], 1);
    }
}

__global__ void scan_a(const int* __restrict__ counts, int* __restrict__ rowptr, int* __restrict__ bsum) {
    __shared__ int s[256];
    int t = threadIdx.x, i = blockIdx.x * 256 + t;
    int v = (i < NN) ? counts[i] : 0;
    s[t] = v;
    __syncthreads();
    for (int off = 1; off < 256; off <<= 1) {
        int add = (t >= off) ? s[t - off] : 0;
        __syncthreads();
        s[t] += add;
        __syncthreads();
    }
    if (i < NN) rowptr[i + 1] = s[t];
    if (t == 255) bsum[blockIdx.x] = s[255];
}

__global__ void scan_b(int* __restrict__ bsum, int nb) {
    __shared__ int s[256];
    int t = threadIdx.x;
    int v = (t < nb) ? bsum[t] : 0;
    s[t] = v;
    __syncthreads();
    for (int off = 1; off < 256; off <<= 1) {
        int add = (t >= off) ? s[t - off] : 0;
        __syncthreads();
        s[t] += add;
        __syncthreads();
    }
    if (t < nb) bsum[t] = s[t] - v;  // exclusive
}

__global__ void scan_c(int* __restrict__ rowptr, const int* __restrict__ bsum) {
    int i = blockIdx.x * 256 + threadIdx.x;
    if (i < NN) rowptr[i + 1] += bsum[i >> 8];
    if (i == 0) rowptr[0] = 0;
}

__global__ void edge_place(const int* __restrict__ ei, const int* __restrict__ rowptr,
                           const int* __restrict__ rank, int* __restrict__ csr) {
    int e = blockIdx.x * 256 + threadIdx.x;
    if (e < ET) {
        int src, dst;
        if (e < NE) { src = ei[e]; dst = ei[NE + e]; }
        else        { src = e - NE; dst = src; }
        csr[rowptr[dst] + rank[e]] = src;
    }
}

// ---------------- bf16 MFMA GEMM + fused s/d epilogue ----------------
// C[M][Nn] = A[M][K] * Bt[Nn][K]^T ; s_arr/d_arr[row][head] = dot(C row-slice, a_s/a_d)
#define BM 128
#define BN 128
#define BK 64
#define LP 72  // BK + 8 pad

template<bool AF32>
__global__ __launch_bounds__(256) void gemm_fused(const void* __restrict__ Ain,
                                                  const unsigned short* __restrict__ Bt,
                                                  unsigned short* __restrict__ C,
                                                  const float* __restrict__ a_s,
                                                  const float* __restrict__ a_d,
                                                  float* __restrict__ s_arr,
                                                  float* __restrict__ d_arr,
                                                  int M, int K, int Nn) {
    __shared__ __align__(16) unsigned short As[BM * LP];
    __shared__ __align__(16) unsigned short Bs[BN * LP];
    int tid = threadIdx.x;
    int lane = tid & 63;
    int w = tid >> 6;
    int wr = w >> 1, wc = w & 1;
    int mBase = blockIdx.x * BM;
    int nBase = blockIdx.y * BN;

    float4v acc[4][4];
    for (int i = 0; i < 4; ++i)
        for (int j = 0; j < 4; ++j)
            acc[i][j] = (float4v){0.f, 0.f, 0.f, 0.f};

    int lm = lane & 15;
    int lk = (lane >> 4) * 8;

    for (int k0 = 0; k0 < K; k0 += BK) {
        if constexpr (AF32) {
            const float* Af = (const float*)Ain;
            for (int p = 0; p < 8; ++p) {
                int chunk = p * 256 + tid;      // 2048 chunks of 4 floats = 128x64
                int row = chunk >> 4;
                int c4 = (chunk & 15) * 4;
                int gm = mBase + row;
                float4 v = make_float4(0.f, 0.f, 0.f, 0.f);
                if (gm < M) v = *(const float4*)(Af + (size_t)gm * K + k0 + c4);
                ushort4v o;
                o.x = f2bf(v.x); o.y = f2bf(v.y); o.z = f2bf(v.z); o.w = f2bf(v.w);
                *(ushort4v*)(&As[row * LP + c4]) = o;
            }
        } else {
            const unsigned short* Ab = (const unsigned short*)Ain;
            for (int p = 0; p < 4; ++p) {
                int chunk = p * 256 + tid;      // 1024 chunks of 8 elems = 128x64
                int row = chunk >> 3;
                int c8 = (chunk & 7) * 8;
                int gm = mBase + row;
                short8 va = {0, 0, 0, 0, 0, 0, 0, 0};
                if (gm < M) va = *(const short8*)(Ab + (size_t)gm * K + k0 + c8);
                *(short8*)(&As[row * LP + c8]) = va;
            }
        }
        for (int p = 0; p < 4; ++p) {
            int chunk = p * 256 + tid;
            int row = chunk >> 3;
            int c8 = (chunk & 7) * 8;
            int gn = nBase + row;
            short8 vb = *(const short8*)(Bt + (size_t)gn * K + k0 + c8);
            *(short8*)(&Bs[row * LP + c8]) = vb;
        }
        __syncthreads();
        for (int ks = 0; ks < BK; ks += 32) {
            short8 af[4], bfr[4];
            for (int i = 0; i < 4; ++i)
                af[i] = *(const short8*)(&As[(wr * 64 + i * 16 + lm) * LP + ks + lk]);
            for (int j = 0; j < 4; ++j)
                bfr[j] = *(const short8*)(&Bs[(wc * 64 + j * 16 + lm) * LP + ks + lk]);
            for (int i = 0; i < 4; ++i)
                for (int j = 0; j < 4; ++j)
                    acc[i][j] = __builtin_amdgcn_mfma_f32_16x16x32_bf16(af[i], bfr[j], acc[i][j], 0, 0, 0);
        }
        __syncthreads();
    }
    // C write
    int q = lane >> 4;
    int lr = q * 4;
    for (int i = 0; i < 4; ++i)
        for (int j = 0; j < 4; ++j) {
            int col = nBase + wc * 64 + j * 16 + lm;
            for (int r = 0; r < 4; ++r) {
                int row = mBase + wr * 64 + i * 16 + lr + r;
                if (row < M) C[(size_t)row * Nn + col] = f2bf(acc[i][j][r]);
            }
        }
    // fused s/d epilogue: this wave owns head = by*2 + wc for its 64 rows
    int head = blockIdx.y * 2 + wc;
    float as_j[4], ad_j[4];
    for (int j = 0; j < 4; ++j) {
        as_j[j] = a_s[head * 64 + j * 16 + lm];
        ad_j[j] = a_d[head * 64 + j * 16 + lm];
    }
    for (int i = 0; i < 4; ++i)
        for (int r = 0; r < 4; ++r) {
            float sp = acc[i][0][r] * as_j[0] + acc[i][1][r] * as_j[1]
                     + acc[i][2][r] * as_j[2] + acc[i][3][r] * as_j[3];
            float dp = acc[i][0][r] * ad_j[0] + acc[i][1][r] * ad_j[1]
                     + acc[i][2][r] * ad_j[2] + acc[i][3][r] * ad_j[3];
            for (int off = 1; off < 16; off <<= 1) {
                sp += __shfl_xor(sp, off);
                dp += __shfl_xor(dp, off);
            }
            int row = mBase + wr * 64 + i * 16 + q * 4 + r;
            if (lm == 0 && row < M) {
                s_arr[row * 4 + head] = sp;
                d_arr[row * 4 + head] = dp;
            }
        }
}

// ---------------- fused softmax-attention aggregation, head-pair split ----------------
// pass p handles heads {2p, 2p+1} = channels [128p, 128p+128).
// per 64-edge chunk: lane e stages {w_h0, w_h1, src}; sweep does 4 edges/iter:
// lane = g*16+lp, g=edge slot, lp = 16B channel group within the 256B half-row.
__global__ __launch_bounds__(256) void agg12_hp(const unsigned short* __restrict__ h,
                                                const float* __restrict__ s_arr, const float* __restrict__ d_arr,
                                                const int* __restrict__ rowptr, const int* __restrict__ csr,
                                                const float* __restrict__ S, const float* __restrict__ T,
                                                unsigned short* __restrict__ out, int pass) {
    __shared__ float wls[4][64 * 3];   // per-wave: 64 edges x {w0,w1,src}
    int lane = threadIdx.x & 63;
    int wv = threadIdx.x >> 6;
    int node = blockIdx.x * 4 + wv;
    if (node >= NN) return;
    int r0 = rowptr[node], r1 = rowptr[node + 1];
    float2 dv = *(const float2*)(d_arr + node * 4 + pass * 2);
    float* wbuf = &wls[wv][0];
    int g = lane >> 4;           // edge slot 0..3
    int lp = lane & 15;          // 8-channel group within 128-ch half row
    int head8 = lp >> 3;         // local head (0/1) of channels lp*8..+7
    const unsigned short* hbase = h + pass * 128 + lp * 8;

    float acc[8] = {0.f, 0.f, 0.f, 0.f, 0.f, 0.f, 0.f, 0.f};
    float den0 = 0.f, den1 = 0.f;

    for (int base = r0; base < r1; base += 64) {
        int cnt = min(64, r1 - base);
        int cpad = (cnt + 3) & ~3;
        if (lane < cnt) {
            int src = csr[base + lane];
            float2 sv = *(const float2*)(s_arr + src * 4 + pass * 2);
            float w0 = __expf(lrelu(sv.x + dv.x));
            float w1 = __expf(lrelu(sv.y + dv.y));
            den0 += w0; den1 += w1;
            float* wp = wbuf + lane * 3;
            wp[0] = w0; wp[1] = w1; wp[2] = __int_as_float(src);
        } else if (lane < cpad) {  // pad to multiple of 4 edges
            float* wp = wbuf + lane * 3;
            wp[0] = 0.f; wp[1] = 0.f; wp[2] = __int_as_float(node);
        }
        for (int k = 0; k < cpad; k += 4) {
            const float* wp = wbuf + (k + g) * 3;
            int src = __float_as_int(wp[2]);
            float wgt = wp[head8];
            short8 hv = *(const short8*)(hbase + (size_t)src * F1);
            acc[0] += wgt * bf2f((unsigned short)hv[0]);
            acc[1] += wgt * bf2f((unsigned short)hv[1]);
            acc[2] += wgt * bf2f((unsigned short)hv[2]);
            acc[3] += wgt * bf2f((unsigned short)hv[3]);
            acc[4] += wgt * bf2f((unsigned short)hv[4]);
            acc[5] += wgt * bf2f((unsigned short)hv[5]);
            acc[6] += wgt * bf2f((unsigned short)hv[6]);
            acc[7] += wgt * bf2f((unsigned short)hv[7]);
        }
    }
    // combine the 4 edge slots (same channels)
    for (int u = 0; u < 8; ++u) {
        acc[u] += __shfl_xor(acc[u], 16);
        acc[u] += __shfl_xor(acc[u], 32);
    }
    // denominators (staged across all 64 lanes)
    for (int off = 32; off; off >>= 1) {
        den0 += __shfl_xor(den0, off);
        den1 += __shfl_xor(den1, off);
    }
    if (g == 0) {
        float inv = 1.f / ((head8 == 0) ? den0 : den1);
        int j = pass * 128 + lp * 8;
        float4 Sv0 = *(const float4*)(S + j);
        float4 Sv1 = *(const float4*)(S + j + 4);
        float4 Tv0 = *(const float4*)(T + j);
        float4 Tv1 = *(const float4*)(T + j + 4);
        short8 o;
        o[0] = (short)f2bf(fmaxf(acc[0] * inv * Sv0.x + Tv0.x, 0.f));
        o[1] = (short)f2bf(fmaxf(acc[1] * inv * Sv0.y + Tv0.y, 0.f));
        o[2] = (short)f2bf(fmaxf(acc[2] * inv * Sv0.z + Tv0.z, 0.f));
        o[3] = (short)f2bf(fmaxf(acc[3] * inv * Sv0.w + Tv0.w, 0.f));
        o[4] = (short)f2bf(fmaxf(acc[4] * inv * Sv1.x + Tv1.x, 0.f));
        o[5] = (short)f2bf(fmaxf(acc[5] * inv * Sv1.y + Tv1.y, 0.f));
        o[6] = (short)f2bf(fmaxf(acc[6] * inv * Sv1.z + Tv1.z, 0.f));
        o[7] = (short)f2bf(fmaxf(acc[7] * inv * Sv1.w + Tv1.w, 0.f));
        *(short8*)(out + (size_t)node * F1 + j) = o;
    }
}

// ---------------- layer-3 GEMM (N=16) + fused s3/d3 ----------------
__global__ __launch_bounds__(256) void gemm3_sd(const unsigned short* __restrict__ A, // [NN][256] bf16
                                                const float* __restrict__ W3,         // [256][16]
                                                const float* __restrict__ as3, const float* __restrict__ ad3,
                                                float* __restrict__ h3, float* __restrict__ s3, float* __restrict__ d3) {
    __shared__ __align__(16) float Ws[256 * 16];
    int tid = threadIdx.x;
    for (int p = tid; p < 1024; p += 256)
        ((float4*)Ws)[p] = ((const float4*)W3)[p];
    __syncthreads();
    int nl = tid >> 2;
    int q = tid & 3;
    int node = blockIdx.x * 64 + nl;
    float acc[16];
    for (int j = 0; j < 16; ++j) acc[j] = 0.f;
    if (node < NN) {
        const unsigned short* ar = A + (size_t)node * F1;
        for (int c = q; c < 32; c += 4) {
            short8 v8 = *(const short8*)(ar + c * 8);
            for (int u = 0; u < 8; ++u) {
                float av = bf2f((unsigned short)v8[u]);
                const float* wr = Ws + (c * 8 + u) * 16;
                float4 w0 = *(const float4*)(wr);
                float4 w1 = *(const float4*)(wr + 4);
                float4 w2 = *(const float4*)(wr + 8);
                float4 w3 = *(const float4*)(wr + 12);
                acc[0]  += av * w0.x; acc[1]  += av * w0.y; acc[2]  += av * w0.z; acc[3]  += av * w0.w;
                acc[4]  += av * w1.x; acc[5]  += av * w1.y; acc[6]  += av * w1.z; acc[7]  += av * w1.w;
                acc[8]  += av * w2.x; acc[9]  += av * w2.y; acc[10] += av * w2.z; acc[11] += av * w2.w;
                acc[12] += av * w3.x; acc[13] += av * w3.y; acc[14] += av * w3.z; acc[15] += av * w3.w;
            }
        }
    }
    for (int j = 0; j < 16; ++j) {
        acc[j] += __shfl_xor(acc[j], 1);
        acc[j] += __shfl_xor(acc[j], 2);
    }
    if (q == 0 && node < NN) {
        float sv = 0.f, dvv = 0.f;
        for (int j = 0; j < 16; ++j) {
            h3[(size_t)node * 16 + j] = acc[j];
            sv += acc[j] * as3[j];
            dvv += acc[j] * ad3[j];
        }
        s3[node] = sv;
        d3[node] = dvv;
    }
}

// ---------------- layer-3 aggregation (H=1, C=16) -> d_out ----------------
__global__ __launch_bounds__(256) void agg3(const float* __restrict__ h3, const float* __restrict__ s3,
                                            const float* __restrict__ d3, const int* __restrict__ rowptr,
                                            const int* __restrict__ csr, const float* __restrict__ b3,
                                            float* __restrict__ out) {
    int lane = threadIdx.x & 63;
    int node = blockIdx.x * 4 + (threadIdx.x >> 6);
    if (node >= NN) return;
    int r0 = rowptr[node], r1 = rowptr[node + 1];
    float dv = d3[node];
    int c = lane & 15, g = lane >> 4;
    float acc = 0.f, den = 0.f;
    for (int e = r0 + g; e < r1; e += 4) {
        int src = csr[e];
        float w = __expf(lrelu(s3[src] + dv));
        den += w;
        acc += w * h3[(size_t)src * 16 + c];
    }
    acc += __shfl_xor(acc, 16); acc += __shfl_xor(acc, 32);
    den += __shfl_xor(den, 16); den += __shfl_xor(den, 32);
    if (lane < 16) out[(size_t)node * 16 + lane] = acc / den + b3[lane];
}

// ---------------- host ----------------
extern "C" void kernel_launch(void* const* d_in, const int* in_sizes, int n_in,
                              void* d_out, int out_size, void* d_ws, size_t ws_size,
                              hipStream_t stream) {
    const float* x   = (const float*)d_in[0];
    const int*   ei  = (const int*)d_in[1];
    const float* W1  = (const float*)d_in[2];
    const float* as1 = (const float*)d_in[3];
    const float* ad1 = (const float*)d_in[4];
    const float* b1  = (const float*)d_in[5];
    const float* g1  = (const float*)d_in[6];
    const float* be1 = (const float*)d_in[7];
    const float* m1  = (const float*)d_in[8];
    const float* v1  = (const float*)d_in[9];
    const float* W2  = (const float*)d_in[10];
    const float* as2 = (const float*)d_in[11];
    const float* ad2 = (const float*)d_in[12];
    const float* b2  = (const float*)d_in[13];
    const float* g2  = (const float*)d_in[14];
    const float* be2 = (const float*)d_in[15];
    const float* m2  = (const float*)d_in[16];
    const float* v2  = (const float*)d_in[17];
    const float* W3  = (const float*)d_in[18];
    const float* as3 = (const float*)d_in[19];
    const float* ad3 = (const float*)d_in[20];
    const float* b3  = (const float*)d_in[21];

    char* w = (char*)d_ws;
    size_t off = 0;
    auto alloc = [&](size_t bytes) -> void* {
        off = (off + 255) & ~(size_t)255;
        void* p = w + off;
        off += bytes;
        return p;
    };
    unsigned short* W1t  = (unsigned short*)alloc(256 * 128 * 2);
    unsigned short* W2t  = (unsigned short*)alloc(256 * 256 * 2);
    unsigned short* Abuf = (unsigned short*)alloc((size_t)NN * F1 * 2);  // h1 / h2
    unsigned short* Bbuf = (unsigned short*)alloc((size_t)NN * F1 * 2);  // out1 / out2
    float* h3    = (float*)alloc((size_t)NN * 16 * 4);
    float* s_arr = (float*)alloc((size_t)NN * 4 * 4);
    float* d_arr = (float*)alloc((size_t)NN * 4 * 4);
    float* s3    = (float*)alloc((size_t)NN * 4);
    float* d3    = (float*)alloc((size_t)NN * 4);
    int* counts  = (int*)alloc((size_t)NN * 4);
    int* rowptr  = (int*)alloc((size_t)(NN + 1) * 4);
    int* rank    = (int*)alloc((size_t)ET * 4);
    int* csr     = (int*)alloc((size_t)ET * 4);
    int* bsum    = (int*)alloc(256 * 4);
    float* S1 = (float*)alloc(F1 * 4);
    float* T1 = (float*)alloc(F1 * 4);
    float* S2 = (float*)alloc(F1 * 4);
    float* T2 = (float*)alloc(F1 * 4);
    float* outp = (float*)d_out;

    int nb_scan = (NN + 255) / 256;        // 196
    int nb_edge = (ET + 255) / 256;        // 3321

    // prep (transposes + BN folds, one launch)
    prep_misc<<<386, 256, 0, stream>>>(W1, W1t, W2, W2t,
                                       b1, g1, be1, m1, v1, S1, T1,
                                       b2, g2, be2, m2, v2, S2, T2);

    // CSR by dst (rank-based)
    hipMemsetAsync(counts, 0, (size_t)NN * 4, stream);
    edge_hist_rank<<<nb_edge, 256, 0, stream>>>(ei, counts, rank);
    scan_a<<<nb_scan, 256, 0, stream>>>(counts, rowptr, bsum);
    scan_b<<<1, 256, 0, stream>>>(bsum, nb_scan);
    scan_c<<<nb_scan, 256, 0, stream>>>(rowptr, bsum);
    edge_place<<<nb_edge, 256, 0, stream>>>(ei, rowptr, rank, csr);

    dim3 ggrid((NN + BM - 1) / BM, F1 / BN);
    int agrid = (NN + 3) / 4;

    // layer 1 (A = x in f32, cast fused into staging; s/d fused into epilogue)
    gemm_fused<true><<<ggrid, 256, 0, stream>>>(x, W1t, Abuf, as1, ad1, s_arr, d_arr, NN, 128, F1);
    agg12_hp<<<agrid, 256, 0, stream>>>(Abuf, s_arr, d_arr, rowptr, csr, S1, T1, Bbuf, 0);
    agg12_hp<<<agrid, 256, 0, stream>>>(Abuf, s_arr, d_arr, rowptr, csr, S1, T1, Bbuf, 1);

    // layer 2
    gemm_fused<false><<<ggrid, 256, 0, stream>>>(Bbuf, W2t, Abuf, as2, ad2, s_arr, d_arr, NN, 256, F1);
    agg12_hp<<<agrid, 256, 0, stream>>>(Abuf, s_arr, d_arr, rowptr, csr, S2, T2, Bbuf, 0);
    agg12_hp<<<agrid, 256, 0, stream>>>(Abuf, s_arr, d_arr, rowptr, csr, S2, T2, Bbuf, 1);

    // layer 3
    gemm3_sd<<<(NN + 63) / 64, 256, 0, stream>>>(Bbuf, W3, as3, ad3, h3, s3, d3);
    agg3<<<agrid, 256, 0, stream>>>(h3, s3, d3, rowptr, csr, b3, outp);
}

// Round 5
// 429.765 us; speedup vs baseline: 1.0189x; 1.0189x over previous
//
#include <hip/hip_runtime.h>
#include <math.h>

#define NN 50000
#define NE 800000
#define ET (NE + NN)          // edges + self loops
#define F1 256                // HEADS*HID
#define NEG 0.2f
#define BN_EPS 1e-5f

typedef __attribute__((ext_vector_type(8))) short short8;
typedef __attribute__((ext_vector_type(4))) float float4v;
typedef __attribute__((ext_vector_type(4))) unsigned short ushort4v;

__device__ __forceinline__ float bf2f(unsigned short u) {
    unsigned int x = ((unsigned int)u) << 16;
    return __builtin_bit_cast(float, x);
}
__device__ __forceinline__ unsigned short f2bf(float f) {
    unsigned int x = __builtin_bit_cast(unsigned int, f);
    unsigned int lsb = (x >> 16) & 1u;
    x += 0x7fffu + lsb;
    return (unsigned short)(x >> 16);
}
__device__ __forceinline__ float lrelu(float x) { return x > 0.f ? x : NEG * x; }

// ---------------- merged prep: W1 transpose, W2 transpose, BN folds ----------------
__global__ void prep_misc(const float* __restrict__ W1, unsigned short* __restrict__ W1t,
                          const float* __restrict__ W2, unsigned short* __restrict__ W2t,
                          const float* __restrict__ b1, const float* __restrict__ g1,
                          const float* __restrict__ be1, const float* __restrict__ m1,
                          const float* __restrict__ v1, float* __restrict__ S1, float* __restrict__ T1,
                          const float* __restrict__ b2, const float* __restrict__ g2,
                          const float* __restrict__ be2, const float* __restrict__ m2,
                          const float* __restrict__ v2, float* __restrict__ S2, float* __restrict__ T2) {
    int blk = blockIdx.x, tid = threadIdx.x;
    if (blk < 128) {               // W1t: [256][128] <- W1 [128][256]
        int id = blk * 256 + tid;
        int n = id >> 7, k = id & 127;
        W1t[id] = f2bf(W1[k * 256 + n]);
    } else if (blk < 384) {        // W2t: [256][256] <- W2 [256][256]
        int id = (blk - 128) * 256 + tid;
        int n = id >> 8, k = id & 255;
        W2t[id] = f2bf(W2[k * 256 + n]);
    } else if (blk == 384) {
        float s = g1[tid] * rsqrtf(v1[tid] + BN_EPS);
        S1[tid] = s;
        T1[tid] = (b1[tid] - m1[tid]) * s + be1[tid];
    } else {
        float s = g2[tid] * rsqrtf(v2[tid] + BN_EPS);
        S2[tid] = s;
        T2[tid] = (b2[tid] - m2[tid]) * s + be2[tid];
    }
}

// ---------------- CSR build (rank-based, single atomic pass) ----------------
__global__ void edge_hist_rank(const int* __restrict__ ei, int* __restrict__ counts, int* __restrict__ rank) {
    int e = blockIdx.x * 256 + threadIdx.x;
    if (e < ET) {
        int dst = (e < NE) ? ei[NE + e] : (e - NE);
        rank[e] = atomicAdd(&counts[dst], 1);
    }
}

__global__ void scan_a(const int* __restrict__ counts, int* __restrict__ rowptr, int* __restrict__ bsum) {
    __shared__ int s[256];
    int t = threadIdx.x, i = blockIdx.x * 256 + t;
    int v = (i < NN) ? counts[i] : 0;
    s[t] = v;
    __syncthreads();
    for (int off = 1; off < 256; off <<= 1) {
        int add = (t >= off) ? s[t - off] : 0;
        __syncthreads();
        s[t] += add;
        __syncthreads();
    }
    if (i < NN) rowptr[i + 1] = s[t];
    if (t == 255) bsum[blockIdx.x] = s[255];
}

__global__ void scan_b(int* __restrict__ bsum, int nb) {
    __shared__ int s[256];
    int t = threadIdx.x;
    int v = (t < nb) ? bsum[t] : 0;
    s[t] = v;
    __syncthreads();
    for (int off = 1; off < 256; off <<= 1) {
        int add = (t >= off) ? s[t - off] : 0;
        __syncthreads();
        s[t] += add;
        __syncthreads();
    }
    if (t < nb) bsum[t] = s[t] - v;  // exclusive
}

__global__ void scan_c(int* __restrict__ rowptr, const int* __restrict__ bsum) {
    int i = blockIdx.x * 256 + threadIdx.x;
    if (i < NN) rowptr[i + 1] += bsum[i >> 8];
    if (i == 0) rowptr[0] = 0;
}

__global__ void edge_place(const int* __restrict__ ei, const int* __restrict__ rowptr,
                           const int* __restrict__ rank, int* __restrict__ csr) {
    int e = blockIdx.x * 256 + threadIdx.x;
    if (e < ET) {
        int src, dst;
        if (e < NE) { src = ei[e]; dst = ei[NE + e]; }
        else        { src = e - NE; dst = src; }
        csr[rowptr[dst] + rank[e]] = src;
    }
}

// ---------------- direct-from-global MFMA GEMM (no LDS, no barriers) ----------------
// C[M][256] = A[M][K] * Bt[256][K]^T ; fused s/d epilogue.
// B (<=128KB) is L2-resident; A rows partitioned across waves; fragments are
// direct global_load_dwordx4 with immediate offsets, register double-buffered.
template<bool AF32, int K>
__global__ __launch_bounds__(256) void gemm_direct(const void* __restrict__ Ain,
                                                   const unsigned short* __restrict__ Bt,
                                                   unsigned short* __restrict__ C,
                                                   const float* __restrict__ a_s,
                                                   const float* __restrict__ a_d,
                                                   float* __restrict__ s_arr,
                                                   float* __restrict__ d_arr,
                                                   int M) {
    constexpr int Nn = 256;
    int tid = threadIdx.x;
    int lane = tid & 63;
    int w = tid >> 6;
    int wr = w >> 1, wc = w & 1;
    int mBase = blockIdx.x * 128;
    int nBase = blockIdx.y * 128;
    int lm = lane & 15, q = lane >> 4, lk = q * 8;

    const unsigned short* pB[4];
    for (int j = 0; j < 4; ++j)
        pB[j] = Bt + (size_t)(nBase + wc * 64 + j * 16 + lm) * K + lk;

    int rowm[4];
    const float* pAf[4];
    const unsigned short* pAb[4];
    for (int i = 0; i < 4; ++i) {
        int r = mBase + wr * 64 + i * 16 + lm;
        rowm[i] = r;
        int rc = (r < M) ? r : (M - 1);     // clamp: reads valid data, row not written
        if constexpr (AF32) pAf[i] = (const float*)Ain + (size_t)rc * K + lk;
        else                pAb[i] = (const unsigned short*)Ain + (size_t)rc * K + lk;
    }

    float4v acc[4][4];
    for (int i = 0; i < 4; ++i)
        for (int j = 0; j < 4; ++j)
            acc[i][j] = (float4v){0.f, 0.f, 0.f, 0.f};

    constexpr int NS = K / 32;
    short8 fa[2][4], fb[2][4];

    auto loadstep = [&](int s, int buf) {
        int ks = s * 32;
        #pragma unroll
        for (int j = 0; j < 4; ++j) fb[buf][j] = *(const short8*)(pB[j] + ks);
        if constexpr (AF32) {
            #pragma unroll
            for (int i = 0; i < 4; ++i) {
                float4 lo = *(const float4*)(pAf[i] + ks);
                float4 hi = *(const float4*)(pAf[i] + ks + 4);
                short8 t;
                t[0] = (short)f2bf(lo.x); t[1] = (short)f2bf(lo.y);
                t[2] = (short)f2bf(lo.z); t[3] = (short)f2bf(lo.w);
                t[4] = (short)f2bf(hi.x); t[5] = (short)f2bf(hi.y);
                t[6] = (short)f2bf(hi.z); t[7] = (short)f2bf(hi.w);
                fa[buf][i] = t;
            }
        } else {
            #pragma unroll
            for (int i = 0; i < 4; ++i) fa[buf][i] = *(const short8*)(pAb[i] + ks);
        }
    };

    loadstep(0, 0);
    #pragma unroll
    for (int s = 0; s < NS; ++s) {
        if (s + 1 < NS) loadstep(s + 1, (s + 1) & 1);
        int b = s & 1;
        #pragma unroll
        for (int i = 0; i < 4; ++i)
            #pragma unroll
            for (int j = 0; j < 4; ++j)
                acc[i][j] = __builtin_amdgcn_mfma_f32_16x16x32_bf16(fa[b][i], fb[b][j], acc[i][j], 0, 0, 0);
    }

    // C write (C/D layout: col=lane&15, row=q*4+reg)
    for (int i = 0; i < 4; ++i)
        for (int j = 0; j < 4; ++j) {
            int col = nBase + wc * 64 + j * 16 + lm;
            for (int r = 0; r < 4; ++r) {
                int row = mBase + wr * 64 + i * 16 + q * 4 + r;
                if (row < M) C[(size_t)row * Nn + col] = f2bf(acc[i][j][r]);
            }
        }
    // fused s/d epilogue: this wave owns head = by*2 + wc for its 64 rows
    int head = blockIdx.y * 2 + wc;
    float as_j[4], ad_j[4];
    for (int j = 0; j < 4; ++j) {
        as_j[j] = a_s[head * 64 + j * 16 + lm];
        ad_j[j] = a_d[head * 64 + j * 16 + lm];
    }
    for (int i = 0; i < 4; ++i)
        for (int r = 0; r < 4; ++r) {
            float sp = acc[i][0][r] * as_j[0] + acc[i][1][r] * as_j[1]
                     + acc[i][2][r] * as_j[2] + acc[i][3][r] * as_j[3];
            float dp = acc[i][0][r] * ad_j[0] + acc[i][1][r] * ad_j[1]
                     + acc[i][2][r] * ad_j[2] + acc[i][3][r] * ad_j[3];
            for (int off = 1; off < 16; off <<= 1) {
                sp += __shfl_xor(sp, off);
                dp += __shfl_xor(dp, off);
            }
            int row = mBase + wr * 64 + i * 16 + q * 4 + r;
            if (lm == 0 && row < M) {
                s_arr[row * 4 + head] = sp;
                d_arr[row * 4 + head] = dp;
            }
        }
}

// ---------------- fused softmax-attention aggregation, layers 1&2 ----------------
// one wave per dst node; per 64-edge chunk: lane e stages weights for edge e,
// then a sweep processing TWO edges per iteration (32 lanes x 16B each).
__global__ __launch_bounds__(256) void agg12(const unsigned short* __restrict__ h,
                                             const float* __restrict__ s_arr, const float* __restrict__ d_arr,
                                             const int* __restrict__ rowptr, const int* __restrict__ csr,
                                             const float* __restrict__ S, const float* __restrict__ T,
                                             unsigned short* __restrict__ out) {
    __shared__ float wls[4][64 * 5];   // per-wave: 64 edges x {w0,w1,w2,w3,src}
    int lane = threadIdx.x & 63;
    int wv = threadIdx.x >> 6;
    int node = blockIdx.x * 4 + wv;
    if (node >= NN) return;
    int r0 = rowptr[node], r1 = rowptr[node + 1];
    float4 dv = *(const float4*)(d_arr + node * 4);
    float* wbuf = &wls[wv][0];
    int lp = lane & 31;          // 8-channel group within row
    int half = lane >> 5;        // which of the 2 edges this iteration
    int head8 = lp >> 3;         // head of channels lp*8..lp*8+7
    const unsigned short* hbase = h + lp * 8;

    float acc[8] = {0.f, 0.f, 0.f, 0.f, 0.f, 0.f, 0.f, 0.f};
    float den0 = 0.f, den1 = 0.f, den2 = 0.f, den3 = 0.f;

    for (int base = r0; base < r1; base += 64) {
        int cnt = min(64, r1 - base);
        if (lane < cnt) {
            int src = csr[base + lane];
            float4 sv = *(const float4*)(s_arr + src * 4);
            float w0 = __expf(lrelu(sv.x + dv.x));
            float w1 = __expf(lrelu(sv.y + dv.y));
            float w2 = __expf(lrelu(sv.z + dv.z));
            float w3 = __expf(lrelu(sv.w + dv.w));
            den0 += w0; den1 += w1; den2 += w2; den3 += w3;
            float* wp = wbuf + lane * 5;
            wp[0] = w0; wp[1] = w1; wp[2] = w2; wp[3] = w3;
            wp[4] = __int_as_float(src);
        } else if (lane == cnt) {  // pad to even edge count
            float* wp = wbuf + lane * 5;
            wp[0] = 0.f; wp[1] = 0.f; wp[2] = 0.f; wp[3] = 0.f;
            wp[4] = __int_as_float(node);
        }
        int cpad = (cnt + 1) & ~1;
        for (int k = 0; k < cpad; k += 2) {
            int k2 = k + half;
            const float* wp = wbuf + k2 * 5;
            int src = __float_as_int(wp[4]);
            float wgt = wp[head8];
            short8 hv = *(const short8*)(hbase + (size_t)src * F1);
            acc[0] += wgt * bf2f((unsigned short)hv[0]);
            acc[1] += wgt * bf2f((unsigned short)hv[1]);
            acc[2] += wgt * bf2f((unsigned short)hv[2]);
            acc[3] += wgt * bf2f((unsigned short)hv[3]);
            acc[4] += wgt * bf2f((unsigned short)hv[4]);
            acc[5] += wgt * bf2f((unsigned short)hv[5]);
            acc[6] += wgt * bf2f((unsigned short)hv[6]);
            acc[7] += wgt * bf2f((unsigned short)hv[7]);
        }
    }
    // combine the two halves (same channels, different edge parity)
    for (int u = 0; u < 8; ++u) acc[u] += __shfl_xor(acc[u], 32);
    // denominators (staged across all 64 lanes)
    for (int off = 32; off; off >>= 1) {
        den0 += __shfl_xor(den0, off);
        den1 += __shfl_xor(den1, off);
        den2 += __shfl_xor(den2, off);
        den3 += __shfl_xor(den3, off);
    }
    if (half == 0) {
        float den = (head8 == 0) ? den0 : (head8 == 1) ? den1 : (head8 == 2) ? den2 : den3;
        float inv = 1.f / den;
        int j = lp * 8;
        float4 Sv0 = *(const float4*)(S + j);
        float4 Sv1 = *(const float4*)(S + j + 4);
        float4 Tv0 = *(const float4*)(T + j);
        float4 Tv1 = *(const float4*)(T + j + 4);
        short8 o;
        o[0] = (short)f2bf(fmaxf(acc[0] * inv * Sv0.x + Tv0.x, 0.f));
        o[1] = (short)f2bf(fmaxf(acc[1] * inv * Sv0.y + Tv0.y, 0.f));
        o[2] = (short)f2bf(fmaxf(acc[2] * inv * Sv0.z + Tv0.z, 0.f));
        o[3] = (short)f2bf(fmaxf(acc[3] * inv * Sv0.w + Tv0.w, 0.f));
        o[4] = (short)f2bf(fmaxf(acc[4] * inv * Sv1.x + Tv1.x, 0.f));
        o[5] = (short)f2bf(fmaxf(acc[5] * inv * Sv1.y + Tv1.y, 0.f));
        o[6] = (short)f2bf(fmaxf(acc[6] * inv * Sv1.z + Tv1.z, 0.f));
        o[7] = (short)f2bf(fmaxf(acc[7] * inv * Sv1.w + Tv1.w, 0.f));
        *(short8*)(out + (size_t)node * F1 + j) = o;
    }
}

// ---------------- layer-3 GEMM (N=16) + fused s3/d3 ----------------
__global__ __launch_bounds__(256) void gemm3_sd(const unsigned short* __restrict__ A, // [NN][256] bf16
                                                const float* __restrict__ W3,         // [256][16]
                                                const float* __restrict__ as3, const float* __restrict__ ad3,
                                                float* __restrict__ h3, float* __restrict__ s3, float* __restrict__ d3) {
    __shared__ __align__(16) float Ws[256 * 16];
    int tid = threadIdx.x;
    for (int p = tid; p < 1024; p += 256)
        ((float4*)Ws)[p] = ((const float4*)W3)[p];
    __syncthreads();
    int nl = tid >> 2;
    int q = tid & 3;
    int node = blockIdx.x * 64 + nl;
    float acc[16];
    for (int j = 0; j < 16; ++j) acc[j] = 0.f;
    if (node < NN) {
        const unsigned short* ar = A + (size_t)node * F1;
        for (int c = q; c < 32; c += 4) {
            short8 v8 = *(const short8*)(ar + c * 8);
            for (int u = 0; u < 8; ++u) {
                float av = bf2f((unsigned short)v8[u]);
                const float* wr = Ws + (c * 8 + u) * 16;
                float4 w0 = *(const float4*)(wr);
                float4 w1 = *(const float4*)(wr + 4);
                float4 w2 = *(const float4*)(wr + 8);
                float4 w3 = *(const float4*)(wr + 12);
                acc[0]  += av * w0.x; acc[1]  += av * w0.y; acc[2]  += av * w0.z; acc[3]  += av * w0.w;
                acc[4]  += av * w1.x; acc[5]  += av * w1.y; acc[6]  += av * w1.z; acc[7]  += av * w1.w;
                acc[8]  += av * w2.x; acc[9]  += av * w2.y; acc[10] += av * w2.z; acc[11] += av * w2.w;
                acc[12] += av * w3.x; acc[13] += av * w3.y; acc[14] += av * w3.z; acc[15] += av * w3.w;
            }
        }
    }
    for (int j = 0; j < 16; ++j) {
        acc[j] += __shfl_xor(acc[j], 1);
        acc[j] += __shfl_xor(acc[j], 2);
    }
    if (q == 0 && node < NN) {
        float sv = 0.f, dvv = 0.f;
        for (int j = 0; j < 16; ++j) {
            h3[(size_t)node * 16 + j] = acc[j];
            sv += acc[j] * as3[j];
            dvv += acc[j] * ad3[j];
        }
        s3[node] = sv;
        d3[node] = dvv;
    }
}

// ---------------- layer-3 aggregation (H=1, C=16) -> d_out ----------------
__global__ __launch_bounds__(256) void agg3(const float* __restrict__ h3, const float* __restrict__ s3,
                                            const float* __restrict__ d3, const int* __restrict__ rowptr,
                                            const int* __restrict__ csr, const float* __restrict__ b3,
                                            float* __restrict__ out) {
    int lane = threadIdx.x & 63;
    int node = blockIdx.x * 4 + (threadIdx.x >> 6);
    if (node >= NN) return;
    int r0 = rowptr[node], r1 = rowptr[node + 1];
    float dv = d3[node];
    int c = lane & 15, g = lane >> 4;
    float acc = 0.f, den = 0.f;
    for (int e = r0 + g; e < r1; e += 4) {
        int src = csr[e];
        float w = __expf(lrelu(s3[src] + dv));
        den += w;
        acc += w * h3[(size_t)src * 16 + c];
    }
    acc += __shfl_xor(acc, 16); acc += __shfl_xor(acc, 32);
    den += __shfl_xor(den, 16); den += __shfl_xor(den, 32);
    if (lane < 16) out[(size_t)node * 16 + lane] = acc / den + b3[lane];
}

// ---------------- host ----------------
extern "C" void kernel_launch(void* const* d_in, const int* in_sizes, int n_in,
                              void* d_out, int out_size, void* d_ws, size_t ws_size,
                              hipStream_t stream) {
    const float* x   = (const float*)d_in[0];
    const int*   ei  = (const int*)d_in[1];
    const float* W1  = (const float*)d_in[2];
    const float* as1 = (const float*)d_in[3];
    const float* ad1 = (const float*)d_in[4];
    const float* b1  = (const float*)d_in[5];
    const float* g1  = (const float*)d_in[6];
    const float* be1 = (const float*)d_in[7];
    const float* m1  = (const float*)d_in[8];
    const float* v1  = (const float*)d_in[9];
    const float* W2  = (const float*)d_in[10];
    const float* as2 = (const float*)d_in[11];
    const float* ad2 = (const float*)d_in[12];
    const float* b2  = (const float*)d_in[13];
    const float* g2  = (const float*)d_in[14];
    const float* be2 = (const float*)d_in[15];
    const float* m2  = (const float*)d_in[16];
    const float* v2  = (const float*)d_in[17];
    const float* W3  = (const float*)d_in[18];
    const float* as3 = (const float*)d_in[19];
    const float* ad3 = (const float*)d_in[20];
    const float* b3  = (const float*)d_in[21];

    char* w = (char*)d_ws;
    size_t off = 0;
    auto alloc = [&](size_t bytes) -> void* {
        off = (off + 255) & ~(size_t)255;
        void* p = w + off;
        off += bytes;
        return p;
    };
    unsigned short* W1t  = (unsigned short*)alloc(256 * 128 * 2);
    unsigned short* W2t  = (unsigned short*)alloc(256 * 256 * 2);
    unsigned short* Abuf = (unsigned short*)alloc((size_t)NN * F1 * 2);  // h1 / h2
    unsigned short* Bbuf = (unsigned short*)alloc((size_t)NN * F1 * 2);  // out1 / out2
    float* h3    = (float*)alloc((size_t)NN * 16 * 4);
    float* s_arr = (float*)alloc((size_t)NN * 4 * 4);
    float* d_arr = (float*)alloc((size_t)NN * 4 * 4);
    float* s3    = (float*)alloc((size_t)NN * 4);
    float* d3    = (float*)alloc((size_t)NN * 4);
    int* counts  = (int*)alloc((size_t)NN * 4);
    int* rowptr  = (int*)alloc((size_t)(NN + 1) * 4);
    int* rank    = (int*)alloc((size_t)ET * 4);
    int* csr     = (int*)alloc((size_t)ET * 4);
    int* bsum    = (int*)alloc(256 * 4);
    float* S1 = (float*)alloc(F1 * 4);
    float* T1 = (float*)alloc(F1 * 4);
    float* S2 = (float*)alloc(F1 * 4);
    float* T2 = (float*)alloc(F1 * 4);
    float* outp = (float*)d_out;

    int nb_scan = (NN + 255) / 256;        // 196
    int nb_edge = (ET + 255) / 256;        // 3321

    // prep (transposes + BN folds, one launch)
    prep_misc<<<386, 256, 0, stream>>>(W1, W1t, W2, W2t,
                                       b1, g1, be1, m1, v1, S1, T1,
                                       b2, g2, be2, m2, v2, S2, T2);

    // CSR by dst (rank-based)
    hipMemsetAsync(counts, 0, (size_t)NN * 4, stream);
    edge_hist_rank<<<nb_edge, 256, 0, stream>>>(ei, counts, rank);
    scan_a<<<nb_scan, 256, 0, stream>>>(counts, rowptr, bsum);
    scan_b<<<1, 256, 0, stream>>>(bsum, nb_scan);
    scan_c<<<nb_scan, 256, 0, stream>>>(rowptr, bsum);
    edge_place<<<nb_edge, 256, 0, stream>>>(ei, rowptr, rank, csr);

    dim3 ggrid((NN + 127) / 128, 2);
    int agrid = (NN + 3) / 4;

    // layer 1 (A = x in f32, cvt fused into fragment load; s/d fused into epilogue)
    gemm_direct<true, 128><<<ggrid, 256, 0, stream>>>(x, W1t, Abuf, as1, ad1, s_arr, d_arr, NN);
    agg12<<<agrid, 256, 0, stream>>>(Abuf, s_arr, d_arr, rowptr, csr, S1, T1, Bbuf);

    // layer 2
    gemm_direct<false, 256><<<ggrid, 256, 0, stream>>>(Bbuf, W2t, Abuf, as2, ad2, s_arr, d_arr, NN);
    agg12<<<agrid, 256, 0, stream>>>(Abuf, s_arr, d_arr, rowptr, csr, S2, T2, Bbuf);

    // layer 3
    gemm3_sd<<<(NN + 63) / 64, 256, 0, stream>>>(Bbuf, W3, as3, ad3, h3, s3, d3);
    agg3<<<agrid, 256, 0, stream>>>(h3, s3, d3, rowptr, csr, b3, outp);
}

// Round 6
// 395.739 us; speedup vs baseline: 1.1065x; 1.0860x over previous
//
#include <hip/hip_runtime.h>
#include <math.h>

#define NN 50000
#define NE 800000
#define ET (NE + NN)          // edges + self loops
#define F1 256                // HEADS*HID
#define NEG 0.2f
#define BN_EPS 1e-5f

typedef __attribute__((ext_vector_type(8))) short short8;
typedef __attribute__((ext_vector_type(4))) float float4v;
typedef __attribute__((ext_vector_type(4))) unsigned short ushort4v;

__device__ __forceinline__ float bf2f(unsigned short u) {
    unsigned int x = ((unsigned int)u) << 16;
    return __builtin_bit_cast(float, x);
}
__device__ __forceinline__ unsigned short f2bf(float f) {
    unsigned int x = __builtin_bit_cast(unsigned int, f);
    unsigned int lsb = (x >> 16) & 1u;
    x += 0x7fffu + lsb;
    return (unsigned short)(x >> 16);
}
__device__ __forceinline__ float lrelu(float x) { return x > 0.f ? x : NEG * x; }

// async global->LDS, 16B per lane; lds dst must be wave-uniform base (+lane*16 implicit)
__device__ __forceinline__ void gl_lds16(const unsigned short* g, unsigned short* l) {
    __builtin_amdgcn_global_load_lds((const __attribute__((address_space(1))) void*)g,
                                     (__attribute__((address_space(3))) void*)l, 16, 0, 0);
}

// ---------------- prep kernels ----------------
__global__ void cast_f32_bf16(const float* __restrict__ in, unsigned short* __restrict__ out, int n4) {
    int i = (blockIdx.x * 256 + threadIdx.x);
    if (i < n4) {
        float4 v = ((const float4*)in)[i];
        ushort4 o;
        o.x = f2bf(v.x); o.y = f2bf(v.y); o.z = f2bf(v.z); o.w = f2bf(v.w);
        ((ushort4*)out)[i] = o;
    }
}

__global__ void prep_misc(const float* __restrict__ W1, unsigned short* __restrict__ W1t,
                          const float* __restrict__ W2, unsigned short* __restrict__ W2t,
                          const float* __restrict__ b1, const float* __restrict__ g1,
                          const float* __restrict__ be1, const float* __restrict__ m1,
                          const float* __restrict__ v1, float* __restrict__ S1, float* __restrict__ T1,
                          const float* __restrict__ b2, const float* __restrict__ g2,
                          const float* __restrict__ be2, const float* __restrict__ m2,
                          const float* __restrict__ v2, float* __restrict__ S2, float* __restrict__ T2) {
    int blk = blockIdx.x, tid = threadIdx.x;
    if (blk < 128) {               // W1t: [256][128] <- W1 [128][256]
        int id = blk * 256 + tid;
        int n = id >> 7, k = id & 127;
        W1t[id] = f2bf(W1[k * 256 + n]);
    } else if (blk < 384) {        // W2t: [256][256] <- W2 [256][256]
        int id = (blk - 128) * 256 + tid;
        int n = id >> 8, k = id & 255;
        W2t[id] = f2bf(W2[k * 256 + n]);
    } else if (blk == 384) {
        float s = g1[tid] * rsqrtf(v1[tid] + BN_EPS);
        S1[tid] = s;
        T1[tid] = (b1[tid] - m1[tid]) * s + be1[tid];
    } else {
        float s = g2[tid] * rsqrtf(v2[tid] + BN_EPS);
        S2[tid] = s;
        T2[tid] = (b2[tid] - m2[tid]) * s + be2[tid];
    }
}

// ---------------- CSR build (rank-based, single atomic pass) ----------------
__global__ void edge_hist_rank(const int* __restrict__ ei, int* __restrict__ counts, int* __restrict__ rank) {
    int e = blockIdx.x * 256 + threadIdx.x;
    if (e < ET) {
        int dst = (e < NE) ? ei[NE + e] : (e - NE);
        rank[e] = atomicAdd(&counts[dst], 1);
    }
}

__global__ void scan_a(const int* __restrict__ counts, int* __restrict__ rowptr, int* __restrict__ bsum) {
    __shared__ int s[256];
    int t = threadIdx.x, i = blockIdx.x * 256 + t;
    int v = (i < NN) ? counts[i] : 0;
    s[t] = v;
    __syncthreads();
    for (int off = 1; off < 256; off <<= 1) {
        int add = (t >= off) ? s[t - off] : 0;
        __syncthreads();
        s[t] += add;
        __syncthreads();
    }
    if (i < NN) rowptr[i + 1] = s[t];
    if (t == 255) bsum[blockIdx.x] = s[255];
}

__global__ void scan_b(int* __restrict__ bsum, int nb) {
    __shared__ int s[256];
    int t = threadIdx.x;
    int v = (t < nb) ? bsum[t] : 0;
    s[t] = v;
    __syncthreads();
    for (int off = 1; off < 256; off <<= 1) {
        int add = (t >= off) ? s[t - off] : 0;
        __syncthreads();
        s[t] += add;
        __syncthreads();
    }
    if (t < nb) bsum[t] = s[t] - v;  // exclusive
}

__global__ void scan_c(int* __restrict__ rowptr, const int* __restrict__ bsum) {
    int i = blockIdx.x * 256 + threadIdx.x;
    if (i < NN) rowptr[i + 1] += bsum[i >> 8];
    if (i == 0) rowptr[0] = 0;
}

__global__ void edge_place(const int* __restrict__ ei, const int* __restrict__ rowptr,
                           const int* __restrict__ rank, int* __restrict__ csr) {
    int e = blockIdx.x * 256 + threadIdx.x;
    if (e < ET) {
        int src, dst;
        if (e < NE) { src = ei[e]; dst = ei[NE + e]; }
        else        { src = e - NE; dst = src; }
        csr[rowptr[dst] + rank[e]] = src;
    }
}

// ---------------- m97-style MFMA GEMM: global_load_lds staging + XOR swizzle ----------------
// C[M][256] = A[M][K] * Bt[256][K]^T, A/Bt bf16. Fused s/d epilogue.
// LDS tiles 128x64 bf16, unpadded pitch 64; 16B chunk c at (row, c^(row&7)).
template<int K>
__global__ __launch_bounds__(256, 3) void gemm_lds(const unsigned short* __restrict__ A,
                                                   const unsigned short* __restrict__ Bt,
                                                   unsigned short* __restrict__ C,
                                                   const float* __restrict__ a_s,
                                                   const float* __restrict__ a_d,
                                                   float* __restrict__ s_arr,
                                                   float* __restrict__ d_arr,
                                                   int M) {
    __shared__ __align__(16) unsigned short As[128 * 64];
    __shared__ __align__(16) unsigned short Bs[128 * 64];
    int tid = threadIdx.x, lane = tid & 63, w = tid >> 6;
    int wr = w >> 1, wc = w & 1;
    int mBase = blockIdx.x * 128, nBase = blockIdx.y * 128;
    int lm = lane & 15, q = lane >> 4;

    float4v acc[4][4];
    for (int i = 0; i < 4; ++i)
        for (int j = 0; j < 4; ++j)
            acc[i][j] = (float4v){0.f, 0.f, 0.f, 0.f};

    // staging map: slot = p*256+tid (1024 slots of 16B); row=slot>>3; ch=slot&7
    // source chunk is swizzled: csrc = ch ^ (row&7); lds slot is natural.
    const unsigned short* Ap[4];
    const unsigned short* Bp[4];
    for (int p = 0; p < 4; ++p) {
        int slot = p * 256 + tid;
        int row = slot >> 3;
        int csrc = (slot & 7) ^ (row & 7);
        int gm = mBase + row; if (gm >= M) gm = M - 1;   // clamp: dup read, rows >=M never written
        Ap[p] = A + (size_t)gm * K + csrc * 8;
        Bp[p] = Bt + (size_t)(nBase + row) * K + csrc * 8;
    }

    for (int k0 = 0; k0 < K; k0 += 64) {
        #pragma unroll
        for (int p = 0; p < 4; ++p)
            gl_lds16(Ap[p] + k0, As + ((size_t)p * 256 + w * 64) * 8);
        #pragma unroll
        for (int p = 0; p < 4; ++p)
            gl_lds16(Bp[p] + k0, Bs + ((size_t)p * 256 + w * 64) * 8);
        __syncthreads();
        #pragma unroll
        for (int ks = 0; ks < 64; ks += 32) {
            int cb = ks >> 3;   // 0 or 4
            short8 af[4], bfr[4];
            #pragma unroll
            for (int i = 0; i < 4; ++i) {
                int row = wr * 64 + i * 16 + lm;
                int ch = (cb + q) ^ (row & 7);
                af[i] = *(const short8*)(As + row * 64 + ch * 8);
            }
            #pragma unroll
            for (int j = 0; j < 4; ++j) {
                int row = wc * 64 + j * 16 + lm;
                int ch = (cb + q) ^ (row & 7);
                bfr[j] = *(const short8*)(Bs + row * 64 + ch * 8);
            }
            #pragma unroll
            for (int i = 0; i < 4; ++i)
                #pragma unroll
                for (int j = 0; j < 4; ++j)
                    acc[i][j] = __builtin_amdgcn_mfma_f32_16x16x32_bf16(af[i], bfr[j], acc[i][j], 0, 0, 0);
        }
        __syncthreads();
    }

    // C write (C/D layout: col=lane&15, row=q*4+reg)
    for (int i = 0; i < 4; ++i)
        for (int j = 0; j < 4; ++j) {
            int col = nBase + wc * 64 + j * 16 + lm;
            for (int r = 0; r < 4; ++r) {
                int row = mBase + wr * 64 + i * 16 + q * 4 + r;
                if (row < M) C[(size_t)row * 256 + col] = f2bf(acc[i][j][r]);
            }
        }
    // fused s/d epilogue: this wave owns head = by*2 + wc for its 64 rows
    int head = blockIdx.y * 2 + wc;
    float as_j[4], ad_j[4];
    for (int j = 0; j < 4; ++j) {
        as_j[j] = a_s[head * 64 + j * 16 + lm];
        ad_j[j] = a_d[head * 64 + j * 16 + lm];
    }
    for (int i = 0; i < 4; ++i)
        for (int r = 0; r < 4; ++r) {
            float sp = acc[i][0][r] * as_j[0] + acc[i][1][r] * as_j[1]
                     + acc[i][2][r] * as_j[2] + acc[i][3][r] * as_j[3];
            float dp = acc[i][0][r] * ad_j[0] + acc[i][1][r] * ad_j[1]
                     + acc[i][2][r] * ad_j[2] + acc[i][3][r] * ad_j[3];
            for (int off = 1; off < 16; off <<= 1) {
                sp += __shfl_xor(sp, off);
                dp += __shfl_xor(dp, off);
            }
            int row = mBase + wr * 64 + i * 16 + q * 4 + r;
            if (lm == 0 && row < M) {
                s_arr[row * 4 + head] = sp;
                d_arr[row * 4 + head] = dp;
            }
        }
}

// ---------------- fused softmax-attention aggregation, layers 1&2 ----------------
__global__ __launch_bounds__(256) void agg12(const unsigned short* __restrict__ h,
                                             const float* __restrict__ s_arr, const float* __restrict__ d_arr,
                                             const int* __restrict__ rowptr, const int* __restrict__ csr,
                                             const float* __restrict__ S, const float* __restrict__ T,
                                             unsigned short* __restrict__ out) {
    __shared__ float wls[4][64 * 5];   // per-wave: 64 edges x {w0,w1,w2,w3,src}
    int lane = threadIdx.x & 63;
    int wv = threadIdx.x >> 6;
    int node = blockIdx.x * 4 + wv;
    if (node >= NN) return;
    int r0 = rowptr[node], r1 = rowptr[node + 1];
    float4 dv = *(const float4*)(d_arr + node * 4);
    float* wbuf = &wls[wv][0];
    int lp = lane & 31;          // 8-channel group within row
    int half = lane >> 5;        // which of the 2 edges this iteration
    int head8 = lp >> 3;         // head of channels lp*8..lp*8+7
    const unsigned short* hbase = h + lp * 8;

    float acc[8] = {0.f, 0.f, 0.f, 0.f, 0.f, 0.f, 0.f, 0.f};
    float den0 = 0.f, den1 = 0.f, den2 = 0.f, den3 = 0.f;

    for (int base = r0; base < r1; base += 64) {
        int cnt = min(64, r1 - base);
        if (lane < cnt) {
            int src = csr[base + lane];
            float4 sv = *(const float4*)(s_arr + src * 4);
            float w0 = __expf(lrelu(sv.x + dv.x));
            float w1 = __expf(lrelu(sv.y + dv.y));
            float w2 = __expf(lrelu(sv.z + dv.z));
            float w3 = __expf(lrelu(sv.w + dv.w));
            den0 += w0; den1 += w1; den2 += w2; den3 += w3;
            float* wp = wbuf + lane * 5;
            wp[0] = w0; wp[1] = w1; wp[2] = w2; wp[3] = w3;
            wp[4] = __int_as_float(src);
        } else if (lane == cnt) {  // pad to even edge count
            float* wp = wbuf + lane * 5;
            wp[0] = 0.f; wp[1] = 0.f; wp[2] = 0.f; wp[3] = 0.f;
            wp[4] = __int_as_float(node);
        }
        int cpad = (cnt + 1) & ~1;
        for (int k = 0; k < cpad; k += 2) {
            int k2 = k + half;
            const float* wp = wbuf + k2 * 5;
            int src = __float_as_int(wp[4]);
            float wgt = wp[head8];
            short8 hv = *(const short8*)(hbase + (size_t)src * F1);
            acc[0] += wgt * bf2f((unsigned short)hv[0]);
            acc[1] += wgt * bf2f((unsigned short)hv[1]);
            acc[2] += wgt * bf2f((unsigned short)hv[2]);
            acc[3] += wgt * bf2f((unsigned short)hv[3]);
            acc[4] += wgt * bf2f((unsigned short)hv[4]);
            acc[5] += wgt * bf2f((unsigned short)hv[5]);
            acc[6] += wgt * bf2f((unsigned short)hv[6]);
            acc[7] += wgt * bf2f((unsigned short)hv[7]);
        }
    }
    for (int u = 0; u < 8; ++u) acc[u] += __shfl_xor(acc[u], 32);
    for (int off = 32; off; off >>= 1) {
        den0 += __shfl_xor(den0, off);
        den1 += __shfl_xor(den1, off);
        den2 += __shfl_xor(den2, off);
        den3 += __shfl_xor(den3, off);
    }
    if (half == 0) {
        float den = (head8 == 0) ? den0 : (head8 == 1) ? den1 : (head8 == 2) ? den2 : den3;
        float inv = 1.f / den;
        int j = lp * 8;
        float4 Sv0 = *(const float4*)(S + j);
        float4 Sv1 = *(const float4*)(S + j + 4);
        float4 Tv0 = *(const float4*)(T + j);
        float4 Tv1 = *(const float4*)(T + j + 4);
        short8 o;
        o[0] = (short)f2bf(fmaxf(acc[0] * inv * Sv0.x + Tv0.x, 0.f));
        o[1] = (short)f2bf(fmaxf(acc[1] * inv * Sv0.y + Tv0.y, 0.f));
        o[2] = (short)f2bf(fmaxf(acc[2] * inv * Sv0.z + Tv0.z, 0.f));
        o[3] = (short)f2bf(fmaxf(acc[3] * inv * Sv0.w + Tv0.w, 0.f));
        o[4] = (short)f2bf(fmaxf(acc[4] * inv * Sv1.x + Tv1.x, 0.f));
        o[5] = (short)f2bf(fmaxf(acc[5] * inv * Sv1.y + Tv1.y, 0.f));
        o[6] = (short)f2bf(fmaxf(acc[6] * inv * Sv1.z + Tv1.z, 0.f));
        o[7] = (short)f2bf(fmaxf(acc[7] * inv * Sv1.w + Tv1.w, 0.f));
        *(short8*)(out + (size_t)node * F1 + j) = o;
    }
}

// ---------------- layer-3 GEMM (N=16) + fused s3/d3 ----------------
__global__ __launch_bounds__(256) void gemm3_sd(const unsigned short* __restrict__ A, // [NN][256] bf16
                                                const float* __restrict__ W3,         // [256][16]
                                                const float* __restrict__ as3, const float* __restrict__ ad3,
                                                float* __restrict__ h3, float* __restrict__ s3, float* __restrict__ d3) {
    __shared__ __align__(16) float Ws[256 * 16];
    int tid = threadIdx.x;
    for (int p = tid; p < 1024; p += 256)
        ((float4*)Ws)[p] = ((const float4*)W3)[p];
    __syncthreads();
    int nl = tid >> 2;
    int q = tid & 3;
    int node = blockIdx.x * 64 + nl;
    float acc[16];
    for (int j = 0; j < 16; ++j) acc[j] = 0.f;
    if (node < NN) {
        const unsigned short* ar = A + (size_t)node * F1;
        for (int c = q; c < 32; c += 4) {
            short8 v8 = *(const short8*)(ar + c * 8);
            for (int u = 0; u < 8; ++u) {
                float av = bf2f((unsigned short)v8[u]);
                const float* wr = Ws + (c * 8 + u) * 16;
                float4 w0 = *(const float4*)(wr);
                float4 w1 = *(const float4*)(wr + 4);
                float4 w2 = *(const float4*)(wr + 8);
                float4 w3 = *(const float4*)(wr + 12);
                acc[0]  += av * w0.x; acc[1]  += av * w0.y; acc[2]  += av * w0.z; acc[3]  += av * w0.w;
                acc[4]  += av * w1.x; acc[5]  += av * w1.y; acc[6]  += av * w1.z; acc[7]  += av * w1.w;
                acc[8]  += av * w2.x; acc[9]  += av * w2.y; acc[10] += av * w2.z; acc[11] += av * w2.w;
                acc[12] += av * w3.x; acc[13] += av * w3.y; acc[14] += av * w3.z; acc[15] += av * w3.w;
            }
        }
    }
    for (int j = 0; j < 16; ++j) {
        acc[j] += __shfl_xor(acc[j], 1);
        acc[j] += __shfl_xor(acc[j], 2);
    }
    if (q == 0 && node < NN) {
        float sv = 0.f, dvv = 0.f;
        for (int j = 0; j < 16; ++j) {
            h3[(size_t)node * 16 + j] = acc[j];
            sv += acc[j] * as3[j];
            dvv += acc[j] * ad3[j];
        }
        s3[node] = sv;
        d3[node] = dvv;
    }
}

// ---------------- layer-3 aggregation (H=1, C=16) -> d_out ----------------
__global__ __launch_bounds__(256) void agg3(const float* __restrict__ h3, const float* __restrict__ s3,
                                            const float* __restrict__ d3, const int* __restrict__ rowptr,
                                            const int* __restrict__ csr, const float* __restrict__ b3,
                                            float* __restrict__ out) {
    int lane = threadIdx.x & 63;
    int node = blockIdx.x * 4 + (threadIdx.x >> 6);
    if (node >= NN) return;
    int r0 = rowptr[node], r1 = rowptr[node + 1];
    float dv = d3[node];
    int c = lane & 15, g = lane >> 4;
    float acc = 0.f, den = 0.f;
    for (int e = r0 + g; e < r1; e += 4) {
        int src = csr[e];
        float w = __expf(lrelu(s3[src] + dv));
        den += w;
        acc += w * h3[(size_t)src * 16 + c];
    }
    acc += __shfl_xor(acc, 16); acc += __shfl_xor(acc, 32);
    den += __shfl_xor(den, 16); den += __shfl_xor(den, 32);
    if (lane < 16) out[(size_t)node * 16 + lane] = acc / den + b3[lane];
}

// ---------------- host ----------------
extern "C" void kernel_launch(void* const* d_in, const int* in_sizes, int n_in,
                              void* d_out, int out_size, void* d_ws, size_t ws_size,
                              hipStream_t stream) {
    const float* x   = (const float*)d_in[0];
    const int*   ei  = (const int*)d_in[1];
    const float* W1  = (const float*)d_in[2];
    const float* as1 = (const float*)d_in[3];
    const float* ad1 = (const float*)d_in[4];
    const float* b1  = (const float*)d_in[5];
    const float* g1  = (const float*)d_in[6];
    const float* be1 = (const float*)d_in[7];
    const float* m1  = (const float*)d_in[8];
    const float* v1  = (const float*)d_in[9];
    const float* W2  = (const float*)d_in[10];
    const float* as2 = (const float*)d_in[11];
    const float* ad2 = (const float*)d_in[12];
    const float* b2  = (const float*)d_in[13];
    const float* g2  = (const float*)d_in[14];
    const float* be2 = (const float*)d_in[15];
    const float* m2  = (const float*)d_in[16];
    const float* v2  = (const float*)d_in[17];
    const float* W3  = (const float*)d_in[18];
    const float* as3 = (const float*)d_in[19];
    const float* ad3 = (const float*)d_in[20];
    const float* b3  = (const float*)d_in[21];

    char* w = (char*)d_ws;
    size_t off = 0;
    auto alloc = [&](size_t bytes) -> void* {
        off = (off + 255) & ~(size_t)255;
        void* p = w + off;
        off += bytes;
        return p;
    };
    unsigned short* xb   = (unsigned short*)alloc((size_t)NN * 128 * 2);
    unsigned short* W1t  = (unsigned short*)alloc(256 * 128 * 2);
    unsigned short* W2t  = (unsigned short*)alloc(256 * 256 * 2);
    unsigned short* Abuf = (unsigned short*)alloc((size_t)NN * F1 * 2);  // h1 / h2
    unsigned short* Bbuf = (unsigned short*)alloc((size_t)NN * F1 * 2);  // out1 / out2
    float* h3    = (float*)alloc((size_t)NN * 16 * 4);
    float* s_arr = (float*)alloc((size_t)NN * 4 * 4);
    float* d_arr = (float*)alloc((size_t)NN * 4 * 4);
    float* s3    = (float*)alloc((size_t)NN * 4);
    float* d3    = (float*)alloc((size_t)NN * 4);
    int* counts  = (int*)alloc((size_t)NN * 4);
    int* rowptr  = (int*)alloc((size_t)(NN + 1) * 4);
    int* rank    = (int*)alloc((size_t)ET * 4);
    int* csr     = (int*)alloc((size_t)ET * 4);
    int* bsum    = (int*)alloc(256 * 4);
    float* S1 = (float*)alloc(F1 * 4);
    float* T1 = (float*)alloc(F1 * 4);
    float* S2 = (float*)alloc(F1 * 4);
    float* T2 = (float*)alloc(F1 * 4);
    float* outp = (float*)d_out;

    int nb_scan = (NN + 255) / 256;        // 196
    int nb_edge = (ET + 255) / 256;        // 3321

    // prep
    cast_f32_bf16<<<(NN * 128 / 4 + 255) / 256, 256, 0, stream>>>(x, xb, NN * 128 / 4);
    prep_misc<<<386, 256, 0, stream>>>(W1, W1t, W2, W2t,
                                       b1, g1, be1, m1, v1, S1, T1,
                                       b2, g2, be2, m2, v2, S2, T2);

    // CSR by dst (rank-based)
    hipMemsetAsync(counts, 0, (size_t)NN * 4, stream);
    edge_hist_rank<<<nb_edge, 256, 0, stream>>>(ei, counts, rank);
    scan_a<<<nb_scan, 256, 0, stream>>>(counts, rowptr, bsum);
    scan_b<<<1, 256, 0, stream>>>(bsum, nb_scan);
    scan_c<<<nb_scan, 256, 0, stream>>>(rowptr, bsum);
    edge_place<<<nb_edge, 256, 0, stream>>>(ei, rowptr, rank, csr);

    dim3 ggrid((NN + 127) / 128, 2);
    int agrid = (NN + 3) / 4;

    // layer 1
    gemm_lds<128><<<ggrid, 256, 0, stream>>>(xb, W1t, Abuf, as1, ad1, s_arr, d_arr, NN);
    agg12<<<agrid, 256, 0, stream>>>(Abuf, s_arr, d_arr, rowptr, csr, S1, T1, Bbuf);

    // layer 2
    gemm_lds<256><<<ggrid, 256, 0, stream>>>(Bbuf, W2t, Abuf, as2, ad2, s_arr, d_arr, NN);
    agg12<<<agrid, 256, 0, stream>>>(Abuf, s_arr, d_arr, rowptr, csr, S2, T2, Bbuf);

    // layer 3
    gemm3_sd<<<(NN + 63) / 64, 256, 0, stream>>>(Bbuf, W3, as3, ad3, h3, s3, d3);
    agg3<<<agrid, 256, 0, stream>>>(h3, s3, d3, rowptr, csr, b3, outp);
}

// Round 7
// 355.995 us; speedup vs baseline: 1.2300x; 1.1116x over previous
//
#include <hip/hip_runtime.h>
#include <math.h>

#define NN 50000
#define NE 800000
#define ET (NE + NN)          // edges + self loops
#define F1 256                // HEADS*HID
#define NEG 0.2f
#define BN_EPS 1e-5f

typedef __attribute__((ext_vector_type(8))) short short8;
typedef __attribute__((ext_vector_type(4))) float float4v;
typedef __attribute__((ext_vector_type(2))) float float2v;
typedef __attribute__((ext_vector_type(4))) unsigned short ushort4v;

__device__ __forceinline__ float bf2f(unsigned short u) {
    unsigned int x = ((unsigned int)u) << 16;
    return __builtin_bit_cast(float, x);
}
__device__ __forceinline__ unsigned short f2bf(float f) {
    unsigned int x = __builtin_bit_cast(unsigned int, f);
    unsigned int lsb = (x >> 16) & 1u;
    x += 0x7fffu + lsb;
    return (unsigned short)(x >> 16);
}
__device__ __forceinline__ unsigned char f2fp8(float f) {
    int p = __builtin_amdgcn_cvt_pk_fp8_f32(f, f, 0, false);
    return (unsigned char)(p & 0xff);
}
__device__ __forceinline__ float lrelu(float x) { return x > 0.f ? x : NEG * x; }

// async global->LDS, 16B per lane; lds dst must be wave-uniform base (+lane*16 implicit)
__device__ __forceinline__ void gl_lds16(const unsigned short* g, unsigned short* l) {
    __builtin_amdgcn_global_load_lds((const __attribute__((address_space(1))) void*)g,
                                     (__attribute__((address_space(3))) void*)l, 16, 0, 0);
}

// ---------------- fused prep: cast x, edge histogram, W transposes, W3 split, BN folds ----------------
// blocks: [0,6250) cast | [6250,9571) hist | [9571,9699) W1t | [9699,9955) W2t
//         [9955,9971) W3 split | 9971 BN1 | 9972 BN2
__global__ void prep_all(const float* __restrict__ x, unsigned short* __restrict__ xb,
                         const int* __restrict__ ei, int* __restrict__ counts, int* __restrict__ rank,
                         const float* __restrict__ W1, unsigned short* __restrict__ W1t,
                         const float* __restrict__ W2, unsigned short* __restrict__ W2t,
                         const float* __restrict__ W3, unsigned short* __restrict__ W3h,
                         unsigned short* __restrict__ W3l,
                         const float* __restrict__ b1, const float* __restrict__ g1,
                         const float* __restrict__ be1, const float* __restrict__ m1,
                         const float* __restrict__ v1, float* __restrict__ S1, float* __restrict__ T1,
                         const float* __restrict__ b2, const float* __restrict__ g2,
                         const float* __restrict__ be2, const float* __restrict__ m2,
                         const float* __restrict__ v2, float* __restrict__ S2, float* __restrict__ T2) {
    int blk = blockIdx.x, tid = threadIdx.x;
    if (blk < 6250) {              // cast x: 1.6M float4s
        int i = blk * 256 + tid;
        float4 v = ((const float4*)x)[i];
        ushort4 o;
        o.x = f2bf(v.x); o.y = f2bf(v.y); o.z = f2bf(v.z); o.w = f2bf(v.w);
        ((ushort4*)xb)[i] = o;
    } else if (blk < 9571) {       // edge histogram + rank
        int e = (blk - 6250) * 256 + tid;
        if (e < ET) {
            int dst = (e < NE) ? ei[NE + e] : (e - NE);
            rank[e] = atomicAdd(&counts[dst], 1);
        }
    } else if (blk < 9699) {       // W1t [256][128] <- W1 [128][256]
        int id = (blk - 9571) * 256 + tid;
        int n = id >> 7, k = id & 127;
        W1t[id] = f2bf(W1[k * 256 + n]);
    } else if (blk < 9955) {       // W2t [256][256] <- W2 [256][256]
        int id = (blk - 9699) * 256 + tid;
        int n = id >> 8, k = id & 255;
        W2t[id] = f2bf(W2[k * 256 + n]);
    } else if (blk < 9971) {       // W3 hi/lo split: W3t [16][256] <- W3 [256][16]
        int id = (blk - 9955) * 256 + tid;
        int n = id >> 8, k = id & 255;
        float v = W3[k * 16 + n];
        unsigned short hi = f2bf(v);
        W3h[id] = hi;
        W3l[id] = f2bf(v - bf2f(hi));
    } else if (blk == 9971) {
        float s = g1[tid] * rsqrtf(v1[tid] + BN_EPS);
        S1[tid] = s;
        T1[tid] = (b1[tid] - m1[tid]) * s + be1[tid];
    } else {
        float s = g2[tid] * rsqrtf(v2[tid] + BN_EPS);
        S2[tid] = s;
        T2[tid] = (b2[tid] - m2[tid]) * s + be2[tid];
    }
}

// ---------------- CSR scan ----------------
__global__ void scan_a(const int* __restrict__ counts, int* __restrict__ rowptr, int* __restrict__ bsum) {
    __shared__ int s[256];
    int t = threadIdx.x, i = blockIdx.x * 256 + t;
    int v = (i < NN) ? counts[i] : 0;
    s[t] = v;
    __syncthreads();
    for (int off = 1; off < 256; off <<= 1) {
        int add = (t >= off) ? s[t - off] : 0;
        __syncthreads();
        s[t] += add;
        __syncthreads();
    }
    if (i < NN) rowptr[i + 1] = s[t];
    if (t == 255) bsum[blockIdx.x] = s[255];
}

__global__ void scan_b(int* __restrict__ bsum, int nb) {
    __shared__ int s[256];
    int t = threadIdx.x;
    int v = (t < nb) ? bsum[t] : 0;
    s[t] = v;
    __syncthreads();
    for (int off = 1; off < 256; off <<= 1) {
        int add = (t >= off) ? s[t - off] : 0;
        __syncthreads();
        s[t] += add;
        __syncthreads();
    }
    if (t < nb) bsum[t] = s[t] - v;  // exclusive
}

__global__ void scan_c(int* __restrict__ rowptr, const int* __restrict__ bsum) {
    int i = blockIdx.x * 256 + threadIdx.x;
    if (i < NN) rowptr[i + 1] += bsum[i >> 8];
    if (i == 0) rowptr[0] = 0;
}

__global__ void edge_place(const int* __restrict__ ei, const int* __restrict__ rowptr,
                           const int* __restrict__ rank, int* __restrict__ csr) {
    int e = blockIdx.x * 256 + threadIdx.x;
    if (e < ET) {
        int src, dst;
        if (e < NE) { src = ei[e]; dst = ei[NE + e]; }
        else        { src = e - NE; dst = src; }
        csr[rowptr[dst] + rank[e]] = src;
    }
}

// ---------------- m97-style MFMA GEMM: global_load_lds staging + XOR swizzle ----------------
// C[M][256] = A[M][K] * Bt[256][K]^T, A/Bt bf16; C stored bf16 or fp8. Fused s/d epilogue.
template<int K, bool F8OUT>
__global__ __launch_bounds__(256, 3) void gemm_lds(const unsigned short* __restrict__ A,
                                                   const unsigned short* __restrict__ Bt,
                                                   void* __restrict__ Cout,
                                                   const float* __restrict__ a_s,
                                                   const float* __restrict__ a_d,
                                                   float* __restrict__ s_arr,
                                                   float* __restrict__ d_arr,
                                                   int M) {
    __shared__ __align__(16) unsigned short As[128 * 64];
    __shared__ __align__(16) unsigned short Bs[128 * 64];
    int tid = threadIdx.x, lane = tid & 63, w = tid >> 6;
    int wr = w >> 1, wc = w & 1;
    int mBase = blockIdx.x * 128, nBase = blockIdx.y * 128;
    int lm = lane & 15, q = lane >> 4;

    float4v acc[4][4];
    for (int i = 0; i < 4; ++i)
        for (int j = 0; j < 4; ++j)
            acc[i][j] = (float4v){0.f, 0.f, 0.f, 0.f};

    const unsigned short* Ap[4];
    const unsigned short* Bp[4];
    for (int p = 0; p < 4; ++p) {
        int slot = p * 256 + tid;
        int row = slot >> 3;
        int csrc = (slot & 7) ^ (row & 7);
        int gm = mBase + row; if (gm >= M) gm = M - 1;   // clamp: dup read, rows >=M never written
        Ap[p] = A + (size_t)gm * K + csrc * 8;
        Bp[p] = Bt + (size_t)(nBase + row) * K + csrc * 8;
    }

    for (int k0 = 0; k0 < K; k0 += 64) {
        #pragma unroll
        for (int p = 0; p < 4; ++p)
            gl_lds16(Ap[p] + k0, As + ((size_t)p * 256 + w * 64) * 8);
        #pragma unroll
        for (int p = 0; p < 4; ++p)
            gl_lds16(Bp[p] + k0, Bs + ((size_t)p * 256 + w * 64) * 8);
        __syncthreads();
        #pragma unroll
        for (int ks = 0; ks < 64; ks += 32) {
            int cb = ks >> 3;
            short8 af[4], bfr[4];
            #pragma unroll
            for (int i = 0; i < 4; ++i) {
                int row = wr * 64 + i * 16 + lm;
                int ch = (cb + q) ^ (row & 7);
                af[i] = *(const short8*)(As + row * 64 + ch * 8);
            }
            #pragma unroll
            for (int j = 0; j < 4; ++j) {
                int row = wc * 64 + j * 16 + lm;
                int ch = (cb + q) ^ (row & 7);
                bfr[j] = *(const short8*)(Bs + row * 64 + ch * 8);
            }
            #pragma unroll
            for (int i = 0; i < 4; ++i)
                #pragma unroll
                for (int j = 0; j < 4; ++j)
                    acc[i][j] = __builtin_amdgcn_mfma_f32_16x16x32_bf16(af[i], bfr[j], acc[i][j], 0, 0, 0);
        }
        __syncthreads();
    }

    // C write (C/D layout: col=lane&15, row=q*4+reg)
    for (int i = 0; i < 4; ++i)
        for (int j = 0; j < 4; ++j) {
            int col = nBase + wc * 64 + j * 16 + lm;
            for (int r = 0; r < 4; ++r) {
                int row = mBase + wr * 64 + i * 16 + q * 4 + r;
                if (row < M) {
                    if constexpr (F8OUT)
                        ((unsigned char*)Cout)[(size_t)row * 256 + col] = f2fp8(acc[i][j][r]);
                    else
                        ((unsigned short*)Cout)[(size_t)row * 256 + col] = f2bf(acc[i][j][r]);
                }
            }
        }
    // fused s/d epilogue: this wave owns head = by*2 + wc for its 64 rows
    int head = blockIdx.y * 2 + wc;
    float as_j[4], ad_j[4];
    for (int j = 0; j < 4; ++j) {
        as_j[j] = a_s[head * 64 + j * 16 + lm];
        ad_j[j] = a_d[head * 64 + j * 16 + lm];
    }
    for (int i = 0; i < 4; ++i)
        for (int r = 0; r < 4; ++r) {
            float sp = acc[i][0][r] * as_j[0] + acc[i][1][r] * as_j[1]
                     + acc[i][2][r] * as_j[2] + acc[i][3][r] * as_j[3];
            float dp = acc[i][0][r] * ad_j[0] + acc[i][1][r] * ad_j[1]
                     + acc[i][2][r] * ad_j[2] + acc[i][3][r] * ad_j[3];
            for (int off = 1; off < 16; off <<= 1) {
                sp += __shfl_xor(sp, off);
                dp += __shfl_xor(dp, off);
            }
            int row = mBase + wr * 64 + i * 16 + q * 4 + r;
            if (lm == 0 && row < M) {
                s_arr[row * 4 + head] = sp;
                d_arr[row * 4 + head] = dp;
            }
        }
}

// ---------------- fused aggregation, layer 1: h in fp8 e4m3 ----------------
__global__ __launch_bounds__(256) void agg12_f8(const unsigned char* __restrict__ h8,
                                                const float* __restrict__ s_arr, const float* __restrict__ d_arr,
                                                const int* __restrict__ rowptr, const int* __restrict__ csr,
                                                const float* __restrict__ S, const float* __restrict__ T,
                                                unsigned short* __restrict__ out) {
    __shared__ float wls[4][64 * 5];
    int lane = threadIdx.x & 63;
    int wv = threadIdx.x >> 6;
    int node = blockIdx.x * 4 + wv;
    if (node >= NN) return;
    int r0 = rowptr[node], r1 = rowptr[node + 1];
    float4 dv = *(const float4*)(d_arr + node * 4);
    float* wbuf = &wls[wv][0];
    int lp = lane & 31;          // 8-channel group
    int half = lane >> 5;        // edge parity
    int head8 = lp >> 3;
    const unsigned char* hbase = h8 + lp * 8;

    float2v a01 = {0.f, 0.f}, a23 = {0.f, 0.f}, a45 = {0.f, 0.f}, a67 = {0.f, 0.f};
    float den0 = 0.f, den1 = 0.f, den2 = 0.f, den3 = 0.f;

    for (int base = r0; base < r1; base += 64) {
        int cnt = min(64, r1 - base);
        if (lane < cnt) {
            int src = csr[base + lane];
            float4 sv = *(const float4*)(s_arr + src * 4);
            float w0 = __expf(lrelu(sv.x + dv.x));
            float w1 = __expf(lrelu(sv.y + dv.y));
            float w2 = __expf(lrelu(sv.z + dv.z));
            float w3 = __expf(lrelu(sv.w + dv.w));
            den0 += w0; den1 += w1; den2 += w2; den3 += w3;
            float* wp = wbuf + lane * 5;
            wp[0] = w0; wp[1] = w1; wp[2] = w2; wp[3] = w3;
            wp[4] = __int_as_float(src);
        } else if (lane == cnt) {
            float* wp = wbuf + lane * 5;
            wp[0] = 0.f; wp[1] = 0.f; wp[2] = 0.f; wp[3] = 0.f;
            wp[4] = __int_as_float(node);
        }
        int cpad = (cnt + 1) & ~1;
        for (int k = 0; k < cpad; k += 2) {
            const float* wp = wbuf + (k + half) * 5;
            int src = __float_as_int(wp[4]);
            float wgt = wp[head8];
            uint2 hv = *(const uint2*)(hbase + (size_t)src * 256);
            float2v c0 = __builtin_amdgcn_cvt_pk_f32_fp8((int)hv.x, false);
            float2v c1 = __builtin_amdgcn_cvt_pk_f32_fp8((int)hv.x, true);
            float2v c2 = __builtin_amdgcn_cvt_pk_f32_fp8((int)hv.y, false);
            float2v c3 = __builtin_amdgcn_cvt_pk_f32_fp8((int)hv.y, true);
            float2v w2v = {wgt, wgt};
            a01 += w2v * c0;
            a23 += w2v * c1;
            a45 += w2v * c2;
            a67 += w2v * c3;
        }
    }
    float acc[8] = {a01.x, a01.y, a23.x, a23.y, a45.x, a45.y, a67.x, a67.y};
    for (int u = 0; u < 8; ++u) acc[u] += __shfl_xor(acc[u], 32);
    for (int off = 32; off; off >>= 1) {
        den0 += __shfl_xor(den0, off);
        den1 += __shfl_xor(den1, off);
        den2 += __shfl_xor(den2, off);
        den3 += __shfl_xor(den3, off);
    }
    if (half == 0) {
        float den = (head8 == 0) ? den0 : (head8 == 1) ? den1 : (head8 == 2) ? den2 : den3;
        float inv = 1.f / den;
        int j = lp * 8;
        float4 Sv0 = *(const float4*)(S + j);
        float4 Sv1 = *(const float4*)(S + j + 4);
        float4 Tv0 = *(const float4*)(T + j);
        float4 Tv1 = *(const float4*)(T + j + 4);
        short8 o;
        o[0] = (short)f2bf(fmaxf(acc[0] * inv * Sv0.x + Tv0.x, 0.f));
        o[1] = (short)f2bf(fmaxf(acc[1] * inv * Sv0.y + Tv0.y, 0.f));
        o[2] = (short)f2bf(fmaxf(acc[2] * inv * Sv0.z + Tv0.z, 0.f));
        o[3] = (short)f2bf(fmaxf(acc[3] * inv * Sv0.w + Tv0.w, 0.f));
        o[4] = (short)f2bf(fmaxf(acc[4] * inv * Sv1.x + Tv1.x, 0.f));
        o[5] = (short)f2bf(fmaxf(acc[5] * inv * Sv1.y + Tv1.y, 0.f));
        o[6] = (short)f2bf(fmaxf(acc[6] * inv * Sv1.z + Tv1.z, 0.f));
        o[7] = (short)f2bf(fmaxf(acc[7] * inv * Sv1.w + Tv1.w, 0.f));
        *(short8*)(out + (size_t)node * F1 + j) = o;
    }
}

// ---------------- fused aggregation, layer 2: h in bf16 (unchanged, roofline-bound) ----------------
__global__ __launch_bounds__(256) void agg12(const unsigned short* __restrict__ h,
                                             const float* __restrict__ s_arr, const float* __restrict__ d_arr,
                                             const int* __restrict__ rowptr, const int* __restrict__ csr,
                                             const float* __restrict__ S, const float* __restrict__ T,
                                             unsigned short* __restrict__ out) {
    __shared__ float wls[4][64 * 5];
    int lane = threadIdx.x & 63;
    int wv = threadIdx.x >> 6;
    int node = blockIdx.x * 4 + wv;
    if (node >= NN) return;
    int r0 = rowptr[node], r1 = rowptr[node + 1];
    float4 dv = *(const float4*)(d_arr + node * 4);
    float* wbuf = &wls[wv][0];
    int lp = lane & 31;
    int half = lane >> 5;
    int head8 = lp >> 3;
    const unsigned short* hbase = h + lp * 8;

    float acc[8] = {0.f, 0.f, 0.f, 0.f, 0.f, 0.f, 0.f, 0.f};
    float den0 = 0.f, den1 = 0.f, den2 = 0.f, den3 = 0.f;

    for (int base = r0; base < r1; base += 64) {
        int cnt = min(64, r1 - base);
        if (lane < cnt) {
            int src = csr[base + lane];
            float4 sv = *(const float4*)(s_arr + src * 4);
            float w0 = __expf(lrelu(sv.x + dv.x));
            float w1 = __expf(lrelu(sv.y + dv.y));
            float w2 = __expf(lrelu(sv.z + dv.z));
            float w3 = __expf(lrelu(sv.w + dv.w));
            den0 += w0; den1 += w1; den2 += w2; den3 += w3;
            float* wp = wbuf + lane * 5;
            wp[0] = w0; wp[1] = w1; wp[2] = w2; wp[3] = w3;
            wp[4] = __int_as_float(src);
        } else if (lane == cnt) {
            float* wp = wbuf + lane * 5;
            wp[0] = 0.f; wp[1] = 0.f; wp[2] = 0.f; wp[3] = 0.f;
            wp[4] = __int_as_float(node);
        }
        int cpad = (cnt + 1) & ~1;
        for (int k = 0; k < cpad; k += 2) {
            const float* wp = wbuf + (k + half) * 5;
            int src = __float_as_int(wp[4]);
            float wgt = wp[head8];
            short8 hv = *(const short8*)(hbase + (size_t)src * F1);
            acc[0] += wgt * bf2f((unsigned short)hv[0]);
            acc[1] += wgt * bf2f((unsigned short)hv[1]);
            acc[2] += wgt * bf2f((unsigned short)hv[2]);
            acc[3] += wgt * bf2f((unsigned short)hv[3]);
            acc[4] += wgt * bf2f((unsigned short)hv[4]);
            acc[5] += wgt * bf2f((unsigned short)hv[5]);
            acc[6] += wgt * bf2f((unsigned short)hv[6]);
            acc[7] += wgt * bf2f((unsigned short)hv[7]);
        }
    }
    for (int u = 0; u < 8; ++u) acc[u] += __shfl_xor(acc[u], 32);
    for (int off = 32; off; off >>= 1) {
        den0 += __shfl_xor(den0, off);
        den1 += __shfl_xor(den1, off);
        den2 += __shfl_xor(den2, off);
        den3 += __shfl_xor(den3, off);
    }
    if (half == 0) {
        float den = (head8 == 0) ? den0 : (head8 == 1) ? den1 : (head8 == 2) ? den2 : den3;
        float inv = 1.f / den;
        int j = lp * 8;
        float4 Sv0 = *(const float4*)(S + j);
        float4 Sv1 = *(const float4*)(S + j + 4);
        float4 Tv0 = *(const float4*)(T + j);
        float4 Tv1 = *(const float4*)(T + j + 4);
        short8 o;
        o[0] = (short)f2bf(fmaxf(acc[0] * inv * Sv0.x + Tv0.x, 0.f));
        o[1] = (short)f2bf(fmaxf(acc[1] * inv * Sv0.y + Tv0.y, 0.f));
        o[2] = (short)f2bf(fmaxf(acc[2] * inv * Sv0.z + Tv0.z, 0.f));
        o[3] = (short)f2bf(fmaxf(acc[3] * inv * Sv0.w + Tv0.w, 0.f));
        o[4] = (short)f2bf(fmaxf(acc[4] * inv * Sv1.x + Tv1.x, 0.f));
        o[5] = (short)f2bf(fmaxf(acc[5] * inv * Sv1.y + Tv1.y, 0.f));
        o[6] = (short)f2bf(fmaxf(acc[6] * inv * Sv1.z + Tv1.z, 0.f));
        o[7] = (short)f2bf(fmaxf(acc[7] * inv * Sv1.w + Tv1.w, 0.f));
        *(short8*)(out + (size_t)node * F1 + j) = o;
    }
}

// ---------------- layer-3 GEMM via MFMA (W3 hi/lo split) + fused s3/d3 ----------------
// each wave: 16-node tile; C[m][n] = A[m][k] W3[k][n], K=256, N=16.
__global__ __launch_bounds__(256) void gemm3_mfma(const unsigned short* __restrict__ A, // [NN][256] bf16
                                                  const unsigned short* __restrict__ W3h, // [16][256]
                                                  const unsigned short* __restrict__ W3l,
                                                  const float* __restrict__ as3, const float* __restrict__ ad3,
                                                  float* __restrict__ h3, float* __restrict__ s3,
                                                  float* __restrict__ d3, int M) {
    int tid = threadIdx.x, lane = tid & 63, w = tid >> 6;
    int mBase = blockIdx.x * 64 + w * 16;
    int lm = lane & 15, q = lane >> 4;
    int row = mBase + lm;
    int rc = (row < M) ? row : (M - 1);
    const unsigned short* pA = A + (size_t)rc * 256 + q * 8;
    const unsigned short* pH = W3h + lm * 256 + q * 8;
    const unsigned short* pL = W3l + lm * 256 + q * 8;
    float4v acc = (float4v){0.f, 0.f, 0.f, 0.f};
    #pragma unroll
    for (int s = 0; s < 8; ++s) {
        short8 a  = *(const short8*)(pA + s * 32);
        short8 bh = *(const short8*)(pH + s * 32);
        short8 bl = *(const short8*)(pL + s * 32);
        acc = __builtin_amdgcn_mfma_f32_16x16x32_bf16(a, bh, acc, 0, 0, 0);
        acc = __builtin_amdgcn_mfma_f32_16x16x32_bf16(a, bl, acc, 0, 0, 0);
    }
    // lane holds C[row=q*4+r][col=lm]
    float a_s = as3[lm], a_d = ad3[lm];
    for (int r = 0; r < 4; ++r) {
        int rw = mBase + q * 4 + r;
        if (rw < M) h3[(size_t)rw * 16 + lm] = acc[r];
        float sp = acc[r] * a_s, dp = acc[r] * a_d;
        for (int off = 1; off < 16; off <<= 1) {
            sp += __shfl_xor(sp, off);
            dp += __shfl_xor(dp, off);
        }
        if (lm == 0 && rw < M) { s3[rw] = sp; d3[rw] = dp; }
    }
}

// ---------------- layer-3 aggregation (H=1, C=16) -> d_out ----------------
__global__ __launch_bounds__(256) void agg3(const float* __restrict__ h3, const float* __restrict__ s3,
                                            const float* __restrict__ d3, const int* __restrict__ rowptr,
                                            const int* __restrict__ csr, const float* __restrict__ b3,
                                            float* __restrict__ out) {
    int lane = threadIdx.x & 63;
    int node = blockIdx.x * 4 + (threadIdx.x >> 6);
    if (node >= NN) return;
    int r0 = rowptr[node], r1 = rowptr[node + 1];
    float dv = d3[node];
    int c = lane & 15, g = lane >> 4;
    float acc = 0.f, den = 0.f;
    for (int e = r0 + g; e < r1; e += 4) {
        int src = csr[e];
        float w = __expf(lrelu(s3[src] + dv));
        den += w;
        acc += w * h3[(size_t)src * 16 + c];
    }
    acc += __shfl_xor(acc, 16); acc += __shfl_xor(acc, 32);
    den += __shfl_xor(den, 16); den += __shfl_xor(den, 32);
    if (lane < 16) out[(size_t)node * 16 + lane] = acc / den + b3[lane];
}

// ---------------- host ----------------
extern "C" void kernel_launch(void* const* d_in, const int* in_sizes, int n_in,
                              void* d_out, int out_size, void* d_ws, size_t ws_size,
                              hipStream_t stream) {
    const float* x   = (const float*)d_in[0];
    const int*   ei  = (const int*)d_in[1];
    const float* W1  = (const float*)d_in[2];
    const float* as1 = (const float*)d_in[3];
    const float* ad1 = (const float*)d_in[4];
    const float* b1  = (const float*)d_in[5];
    const float* g1  = (const float*)d_in[6];
    const float* be1 = (const float*)d_in[7];
    const float* m1  = (const float*)d_in[8];
    const float* v1  = (const float*)d_in[9];
    const float* W2  = (const float*)d_in[10];
    const float* as2 = (const float*)d_in[11];
    const float* ad2 = (const float*)d_in[12];
    const float* b2  = (const float*)d_in[13];
    const float* g2  = (const float*)d_in[14];
    const float* be2 = (const float*)d_in[15];
    const float* m2  = (const float*)d_in[16];
    const float* v2  = (const float*)d_in[17];
    const float* W3  = (const float*)d_in[18];
    const float* as3 = (const float*)d_in[19];
    const float* ad3 = (const float*)d_in[20];
    const float* b3  = (const float*)d_in[21];

    char* w = (char*)d_ws;
    size_t off = 0;
    auto alloc = [&](size_t bytes) -> void* {
        off = (off + 255) & ~(size_t)255;
        void* p = w + off;
        off += bytes;
        return p;
    };
    unsigned short* xb    = (unsigned short*)alloc((size_t)NN * 128 * 2);
    unsigned short* W1t   = (unsigned short*)alloc(256 * 128 * 2);
    unsigned short* W2t   = (unsigned short*)alloc(256 * 256 * 2);
    unsigned short* W3h   = (unsigned short*)alloc(16 * 256 * 2);
    unsigned short* W3l   = (unsigned short*)alloc(16 * 256 * 2);
    unsigned char*  Abuf8 = (unsigned char*)alloc((size_t)NN * F1);      // h1 fp8
    unsigned short* Abuf  = (unsigned short*)alloc((size_t)NN * F1 * 2); // h2 bf16
    unsigned short* Bbuf  = (unsigned short*)alloc((size_t)NN * F1 * 2); // out1 / out2
    float* h3    = (float*)alloc((size_t)NN * 16 * 4);
    float* s_arr = (float*)alloc((size_t)NN * 4 * 4);
    float* d_arr = (float*)alloc((size_t)NN * 4 * 4);
    float* s3    = (float*)alloc((size_t)NN * 4);
    float* d3    = (float*)alloc((size_t)NN * 4);
    int* counts  = (int*)alloc((size_t)NN * 4);
    int* rowptr  = (int*)alloc((size_t)(NN + 1) * 4);
    int* rank    = (int*)alloc((size_t)ET * 4);
    int* csr     = (int*)alloc((size_t)ET * 4);
    int* bsum    = (int*)alloc(256 * 4);
    float* S1 = (float*)alloc(F1 * 4);
    float* T1 = (float*)alloc(F1 * 4);
    float* S2 = (float*)alloc(F1 * 4);
    float* T2 = (float*)alloc(F1 * 4);
    float* outp = (float*)d_out;

    int nb_scan = (NN + 255) / 256;        // 196
    int nb_edge = (ET + 255) / 256;        // 3321

    hipMemsetAsync(counts, 0, (size_t)NN * 4, stream);
    prep_all<<<9973, 256, 0, stream>>>(x, xb, ei, counts, rank,
                                       W1, W1t, W2, W2t, W3, W3h, W3l,
                                       b1, g1, be1, m1, v1, S1, T1,
                                       b2, g2, be2, m2, v2, S2, T2);
    scan_a<<<nb_scan, 256, 0, stream>>>(counts, rowptr, bsum);
    scan_b<<<1, 256, 0, stream>>>(bsum, nb_scan);
    scan_c<<<nb_scan, 256, 0, stream>>>(rowptr, bsum);
    edge_place<<<nb_edge, 256, 0, stream>>>(ei, rowptr, rank, csr);

    dim3 ggrid((NN + 127) / 128, 2);
    int agrid = (NN + 3) / 4;

    // layer 1 (C in fp8: h1 only feeds agg1 messages)
    gemm_lds<128, true><<<ggrid, 256, 0, stream>>>(xb, W1t, Abuf8, as1, ad1, s_arr, d_arr, NN);
    agg12_f8<<<agrid, 256, 0, stream>>>(Abuf8, s_arr, d_arr, rowptr, csr, S1, T1, Bbuf);

    // layer 2 (bf16 throughout)
    gemm_lds<256, false><<<ggrid, 256, 0, stream>>>(Bbuf, W2t, Abuf, as2, ad2, s_arr, d_arr, NN);
    agg12<<<agrid, 256, 0, stream>>>(Abuf, s_arr, d_arr, rowptr, csr, S2, T2, Bbuf);

    // layer 3
    gemm3_mfma<<<(NN + 63) / 64, 256, 0, stream>>>(Bbuf, W3h, W3l, as3, ad3, h3, s3, d3, NN);
    agg3<<<agrid, 256, 0, stream>>>(h3, s3, d3, rowptr, csr, b3, outp);
}

// Round 8
// 339.916 us; speedup vs baseline: 1.2882x; 1.0473x over previous
//
#include <hip/hip_runtime.h>
#include <math.h>

#define NN 50000
#define NE 800000
#define ET (NE + NN)          // edges + self loops
#define F1 256                // HEADS*HID
#define NEG 0.2f
#define BN_EPS 1e-5f

typedef __attribute__((ext_vector_type(8))) short short8;
typedef __attribute__((ext_vector_type(4))) float float4v;
typedef __attribute__((ext_vector_type(2))) float float2v;
typedef __attribute__((ext_vector_type(4))) unsigned short ushort4v;

__device__ __forceinline__ float bf2f(unsigned short u) {
    unsigned int x = ((unsigned int)u) << 16;
    return __builtin_bit_cast(float, x);
}
__device__ __forceinline__ unsigned short f2bf(float f) {
    unsigned int x = __builtin_bit_cast(unsigned int, f);
    unsigned int lsb = (x >> 16) & 1u;
    x += 0x7fffu + lsb;
    return (unsigned short)(x >> 16);
}
__device__ __forceinline__ unsigned char f2fp8(float f) {
    int p = __builtin_amdgcn_cvt_pk_fp8_f32(f, f, 0, false);
    return (unsigned char)(p & 0xff);
}
__device__ __forceinline__ float lrelu(float x) { return x > 0.f ? x : NEG * x; }

// async global->LDS, 16B per lane; lds dst must be wave-uniform base (+lane*16 implicit)
__device__ __forceinline__ void gl_lds16(const unsigned short* g, unsigned short* l) {
    __builtin_amdgcn_global_load_lds((const __attribute__((address_space(1))) void*)g,
                                     (__attribute__((address_space(3))) void*)l, 16, 0, 0);
}

// ---------------- fused prep: cast x, edge histogram, W transposes, W3 split, BN folds ----------------
__global__ void prep_all(const float* __restrict__ x, unsigned short* __restrict__ xb,
                         const int* __restrict__ ei, int* __restrict__ counts, int* __restrict__ rank,
                         const float* __restrict__ W1, unsigned short* __restrict__ W1t,
                         const float* __restrict__ W2, unsigned short* __restrict__ W2t,
                         const float* __restrict__ W3, unsigned short* __restrict__ W3h,
                         unsigned short* __restrict__ W3l,
                         const float* __restrict__ b1, const float* __restrict__ g1,
                         const float* __restrict__ be1, const float* __restrict__ m1,
                         const float* __restrict__ v1, float* __restrict__ S1, float* __restrict__ T1,
                         const float* __restrict__ b2, const float* __restrict__ g2,
                         const float* __restrict__ be2, const float* __restrict__ m2,
                         const float* __restrict__ v2, float* __restrict__ S2, float* __restrict__ T2) {
    int blk = blockIdx.x, tid = threadIdx.x;
    if (blk < 6250) {              // cast x: 1.6M float4s
        int i = blk * 256 + tid;
        float4 v = ((const float4*)x)[i];
        ushort4 o;
        o.x = f2bf(v.x); o.y = f2bf(v.y); o.z = f2bf(v.z); o.w = f2bf(v.w);
        ((ushort4*)xb)[i] = o;
    } else if (blk < 9571) {       // edge histogram + rank
        int e = (blk - 6250) * 256 + tid;
        if (e < ET) {
            int dst = (e < NE) ? ei[NE + e] : (e - NE);
            rank[e] = atomicAdd(&counts[dst], 1);
        }
    } else if (blk < 9699) {       // W1t [256][128] <- W1 [128][256]
        int id = (blk - 9571) * 256 + tid;
        int n = id >> 7, k = id & 127;
        W1t[id] = f2bf(W1[k * 256 + n]);
    } else if (blk < 9955) {       // W2t [256][256] <- W2 [256][256]
        int id = (blk - 9699) * 256 + tid;
        int n = id >> 8, k = id & 255;
        W2t[id] = f2bf(W2[k * 256 + n]);
    } else if (blk < 9971) {       // W3 hi/lo split: W3t [16][256] <- W3 [256][16]
        int id = (blk - 9955) * 256 + tid;
        int n = id >> 8, k = id & 255;
        float v = W3[k * 16 + n];
        unsigned short hi = f2bf(v);
        W3h[id] = hi;
        W3l[id] = f2bf(v - bf2f(hi));
    } else if (blk == 9971) {
        float s = g1[tid] * rsqrtf(v1[tid] + BN_EPS);
        S1[tid] = s;
        T1[tid] = (b1[tid] - m1[tid]) * s + be1[tid];
    } else {
        float s = g2[tid] * rsqrtf(v2[tid] + BN_EPS);
        S2[tid] = s;
        T2[tid] = (b2[tid] - m2[tid]) * s + be2[tid];
    }
}

// ---------------- CSR scan ----------------
__global__ void scan_a(const int* __restrict__ counts, int* __restrict__ rowptr, int* __restrict__ bsum) {
    __shared__ int s[256];
    int t = threadIdx.x, i = blockIdx.x * 256 + t;
    int v = (i < NN) ? counts[i] : 0;
    s[t] = v;
    __syncthreads();
    for (int off = 1; off < 256; off <<= 1) {
        int add = (t >= off) ? s[t - off] : 0;
        __syncthreads();
        s[t] += add;
        __syncthreads();
    }
    if (i < NN) rowptr[i + 1] = s[t];
    if (t == 255) bsum[blockIdx.x] = s[255];
}

// merged: each block reduces bsum[0..bid) and offsets its rowptr slice
__global__ void scan_bc(int* __restrict__ rowptr, const int* __restrict__ bsum, int nb) {
    __shared__ int s[256];
    int t = threadIdx.x, bid = blockIdx.x;
    s[t] = (t < bid && t < nb) ? bsum[t] : 0;
    __syncthreads();
    for (int off = 128; off; off >>= 1) {
        if (t < off) s[t] += s[t + off];
        __syncthreads();
    }
    int add = s[0];
    int i = bid * 256 + t;
    if (i < NN) rowptr[i + 1] += add;
    if (i == 0) rowptr[0] = 0;
}

__global__ void edge_place(const int* __restrict__ ei, const int* __restrict__ rowptr,
                           const int* __restrict__ rank, int* __restrict__ csr) {
    int e = blockIdx.x * 256 + threadIdx.x;
    if (e < ET) {
        int src, dst;
        if (e < NE) { src = ei[e]; dst = ei[NE + e]; }
        else        { src = e - NE; dst = src; }
        csr[rowptr[dst] + rank[e]] = src;
    }
}

// ---------------- m97-style MFMA GEMM: global_load_lds staging + XOR swizzle ----------------
template<int K, bool F8OUT>
__global__ __launch_bounds__(256, 3) void gemm_lds(const unsigned short* __restrict__ A,
                                                   const unsigned short* __restrict__ Bt,
                                                   void* __restrict__ Cout,
                                                   const float* __restrict__ a_s,
                                                   const float* __restrict__ a_d,
                                                   float* __restrict__ s_arr,
                                                   float* __restrict__ d_arr,
                                                   int M) {
    __shared__ __align__(16) unsigned short As[128 * 64];
    __shared__ __align__(16) unsigned short Bs[128 * 64];
    int tid = threadIdx.x, lane = tid & 63, w = tid >> 6;
    int wr = w >> 1, wc = w & 1;
    int mBase = blockIdx.x * 128, nBase = blockIdx.y * 128;
    int lm = lane & 15, q = lane >> 4;

    float4v acc[4][4];
    for (int i = 0; i < 4; ++i)
        for (int j = 0; j < 4; ++j)
            acc[i][j] = (float4v){0.f, 0.f, 0.f, 0.f};

    const unsigned short* Ap[4];
    const unsigned short* Bp[4];
    for (int p = 0; p < 4; ++p) {
        int slot = p * 256 + tid;
        int row = slot >> 3;
        int csrc = (slot & 7) ^ (row & 7);
        int gm = mBase + row; if (gm >= M) gm = M - 1;   // clamp: dup read, rows >=M never written
        Ap[p] = A + (size_t)gm * K + csrc * 8;
        Bp[p] = Bt + (size_t)(nBase + row) * K + csrc * 8;
    }

    for (int k0 = 0; k0 < K; k0 += 64) {
        #pragma unroll
        for (int p = 0; p < 4; ++p)
            gl_lds16(Ap[p] + k0, As + ((size_t)p * 256 + w * 64) * 8);
        #pragma unroll
        for (int p = 0; p < 4; ++p)
            gl_lds16(Bp[p] + k0, Bs + ((size_t)p * 256 + w * 64) * 8);
        __syncthreads();
        #pragma unroll
        for (int ks = 0; ks < 64; ks += 32) {
            int cb = ks >> 3;
            short8 af[4], bfr[4];
            #pragma unroll
            for (int i = 0; i < 4; ++i) {
                int row = wr * 64 + i * 16 + lm;
                int ch = (cb + q) ^ (row & 7);
                af[i] = *(const short8*)(As + row * 64 + ch * 8);
            }
            #pragma unroll
            for (int j = 0; j < 4; ++j) {
                int row = wc * 64 + j * 16 + lm;
                int ch = (cb + q) ^ (row & 7);
                bfr[j] = *(const short8*)(Bs + row * 64 + ch * 8);
            }
            #pragma unroll
            for (int i = 0; i < 4; ++i)
                #pragma unroll
                for (int j = 0; j < 4; ++j)
                    acc[i][j] = __builtin_amdgcn_mfma_f32_16x16x32_bf16(af[i], bfr[j], acc[i][j], 0, 0, 0);
        }
        __syncthreads();
    }

    // C write (C/D layout: col=lane&15, row=q*4+reg)
    for (int i = 0; i < 4; ++i)
        for (int j = 0; j < 4; ++j) {
            int col = nBase + wc * 64 + j * 16 + lm;
            for (int r = 0; r < 4; ++r) {
                int row = mBase + wr * 64 + i * 16 + q * 4 + r;
                if (row < M) {
                    if constexpr (F8OUT)
                        ((unsigned char*)Cout)[(size_t)row * 256 + col] = f2fp8(acc[i][j][r]);
                    else
                        ((unsigned short*)Cout)[(size_t)row * 256 + col] = f2bf(acc[i][j][r]);
                }
            }
        }
    // fused s/d epilogue: this wave owns head = by*2 + wc for its 64 rows
    int head = blockIdx.y * 2 + wc;
    float as_j[4], ad_j[4];
    for (int j = 0; j < 4; ++j) {
        as_j[j] = a_s[head * 64 + j * 16 + lm];
        ad_j[j] = a_d[head * 64 + j * 16 + lm];
    }
    for (int i = 0; i < 4; ++i)
        for (int r = 0; r < 4; ++r) {
            float sp = acc[i][0][r] * as_j[0] + acc[i][1][r] * as_j[1]
                     + acc[i][2][r] * as_j[2] + acc[i][3][r] * as_j[3];
            float dp = acc[i][0][r] * ad_j[0] + acc[i][1][r] * ad_j[1]
                     + acc[i][2][r] * ad_j[2] + acc[i][3][r] * ad_j[3];
            for (int off = 1; off < 16; off <<= 1) {
                sp += __shfl_xor(sp, off);
                dp += __shfl_xor(dp, off);
            }
            int row = mBase + wr * 64 + i * 16 + q * 4 + r;
            if (lm == 0 && row < M) {
                s_arr[row * 4 + head] = sp;
                d_arr[row * 4 + head] = dp;
            }
        }
}

// ---------------- fused aggregation, layer 1: h in fp8 e4m3 (sweep unrolled x2) ----------------
__global__ __launch_bounds__(256) void agg12_f8(const unsigned char* __restrict__ h8,
                                                const float* __restrict__ s_arr, const float* __restrict__ d_arr,
                                                const int* __restrict__ rowptr, const int* __restrict__ csr,
                                                const float* __restrict__ S, const float* __restrict__ T,
                                                unsigned short* __restrict__ out) {
    __shared__ float wls[4][64 * 5];
    int lane = threadIdx.x & 63;
    int wv = threadIdx.x >> 6;
    int node = blockIdx.x * 4 + wv;
    if (node >= NN) return;
    int r0 = rowptr[node], r1 = rowptr[node + 1];
    float4 dv = *(const float4*)(d_arr + node * 4);
    float* wbuf = &wls[wv][0];
    int lp = lane & 31;
    int half = lane >> 5;
    int head8 = lp >> 3;
    const unsigned char* hbase = h8 + lp * 8;

    float2v a01 = {0.f, 0.f}, a23 = {0.f, 0.f}, a45 = {0.f, 0.f}, a67 = {0.f, 0.f};
    float den0 = 0.f, den1 = 0.f, den2 = 0.f, den3 = 0.f;

    for (int base = r0; base < r1; base += 64) {
        int cnt = min(64, r1 - base);
        int cpad = (cnt + 3) & ~3;
        if (lane < cnt) {
            int src = csr[base + lane];
            float4 sv = *(const float4*)(s_arr + src * 4);
            float w0 = __expf(lrelu(sv.x + dv.x));
            float w1 = __expf(lrelu(sv.y + dv.y));
            float w2 = __expf(lrelu(sv.z + dv.z));
            float w3 = __expf(lrelu(sv.w + dv.w));
            den0 += w0; den1 += w1; den2 += w2; den3 += w3;
            float* wp = wbuf + lane * 5;
            wp[0] = w0; wp[1] = w1; wp[2] = w2; wp[3] = w3;
            wp[4] = __int_as_float(src);
        } else if (lane < cpad) {
            float* wp = wbuf + lane * 5;
            wp[0] = 0.f; wp[1] = 0.f; wp[2] = 0.f; wp[3] = 0.f;
            wp[4] = __int_as_float(node);
        }
        for (int k = 0; k < cpad; k += 4) {
            const float* wpA = wbuf + (k + half) * 5;
            const float* wpB = wpA + 10;
            int srcA = __float_as_int(wpA[4]);
            int srcB = __float_as_int(wpB[4]);
            float wgtA = wpA[head8];
            float wgtB = wpB[head8];
            uint2 hvA = *(const uint2*)(hbase + (size_t)srcA * 256);
            uint2 hvB = *(const uint2*)(hbase + (size_t)srcB * 256);
            float2v wA = {wgtA, wgtA}, wB = {wgtB, wgtB};
            a01 += wA * __builtin_amdgcn_cvt_pk_f32_fp8((int)hvA.x, false);
            a23 += wA * __builtin_amdgcn_cvt_pk_f32_fp8((int)hvA.x, true);
            a45 += wA * __builtin_amdgcn_cvt_pk_f32_fp8((int)hvA.y, false);
            a67 += wA * __builtin_amdgcn_cvt_pk_f32_fp8((int)hvA.y, true);
            a01 += wB * __builtin_amdgcn_cvt_pk_f32_fp8((int)hvB.x, false);
            a23 += wB * __builtin_amdgcn_cvt_pk_f32_fp8((int)hvB.x, true);
            a45 += wB * __builtin_amdgcn_cvt_pk_f32_fp8((int)hvB.y, false);
            a67 += wB * __builtin_amdgcn_cvt_pk_f32_fp8((int)hvB.y, true);
        }
    }
    float acc[8] = {a01.x, a01.y, a23.x, a23.y, a45.x, a45.y, a67.x, a67.y};
    for (int u = 0; u < 8; ++u) acc[u] += __shfl_xor(acc[u], 32);
    for (int off = 32; off; off >>= 1) {
        den0 += __shfl_xor(den0, off);
        den1 += __shfl_xor(den1, off);
        den2 += __shfl_xor(den2, off);
        den3 += __shfl_xor(den3, off);
    }
    if (half == 0) {
        float den = (head8 == 0) ? den0 : (head8 == 1) ? den1 : (head8 == 2) ? den2 : den3;
        float inv = 1.f / den;
        int j = lp * 8;
        float4 Sv0 = *(const float4*)(S + j);
        float4 Sv1 = *(const float4*)(S + j + 4);
        float4 Tv0 = *(const float4*)(T + j);
        float4 Tv1 = *(const float4*)(T + j + 4);
        short8 o;
        o[0] = (short)f2bf(fmaxf(acc[0] * inv * Sv0.x + Tv0.x, 0.f));
        o[1] = (short)f2bf(fmaxf(acc[1] * inv * Sv0.y + Tv0.y, 0.f));
        o[2] = (short)f2bf(fmaxf(acc[2] * inv * Sv0.z + Tv0.z, 0.f));
        o[3] = (short)f2bf(fmaxf(acc[3] * inv * Sv0.w + Tv0.w, 0.f));
        o[4] = (short)f2bf(fmaxf(acc[4] * inv * Sv1.x + Tv1.x, 0.f));
        o[5] = (short)f2bf(fmaxf(acc[5] * inv * Sv1.y + Tv1.y, 0.f));
        o[6] = (short)f2bf(fmaxf(acc[6] * inv * Sv1.z + Tv1.z, 0.f));
        o[7] = (short)f2bf(fmaxf(acc[7] * inv * Sv1.w + Tv1.w, 0.f));
        *(short8*)(out + (size_t)node * F1 + j) = o;
    }
}

// ---------------- fused aggregation, layer 2: h in bf16 (sweep unrolled x2) ----------------
__global__ __launch_bounds__(256) void agg12(const unsigned short* __restrict__ h,
                                             const float* __restrict__ s_arr, const float* __restrict__ d_arr,
                                             const int* __restrict__ rowptr, const int* __restrict__ csr,
                                             const float* __restrict__ S, const float* __restrict__ T,
                                             unsigned short* __restrict__ out) {
    __shared__ float wls[4][64 * 5];
    int lane = threadIdx.x & 63;
    int wv = threadIdx.x >> 6;
    int node = blockIdx.x * 4 + wv;
    if (node >= NN) return;
    int r0 = rowptr[node], r1 = rowptr[node + 1];
    float4 dv = *(const float4*)(d_arr + node * 4);
    float* wbuf = &wls[wv][0];
    int lp = lane & 31;
    int half = lane >> 5;
    int head8 = lp >> 3;
    const unsigned short* hbase = h + lp * 8;

    float acc[8] = {0.f, 0.f, 0.f, 0.f, 0.f, 0.f, 0.f, 0.f};
    float den0 = 0.f, den1 = 0.f, den2 = 0.f, den3 = 0.f;

    for (int base = r0; base < r1; base += 64) {
        int cnt = min(64, r1 - base);
        int cpad = (cnt + 3) & ~3;
        if (lane < cnt) {
            int src = csr[base + lane];
            float4 sv = *(const float4*)(s_arr + src * 4);
            float w0 = __expf(lrelu(sv.x + dv.x));
            float w1 = __expf(lrelu(sv.y + dv.y));
            float w2 = __expf(lrelu(sv.z + dv.z));
            float w3 = __expf(lrelu(sv.w + dv.w));
            den0 += w0; den1 += w1; den2 += w2; den3 += w3;
            float* wp = wbuf + lane * 5;
            wp[0] = w0; wp[1] = w1; wp[2] = w2; wp[3] = w3;
            wp[4] = __int_as_float(src);
        } else if (lane < cpad) {
            float* wp = wbuf + lane * 5;
            wp[0] = 0.f; wp[1] = 0.f; wp[2] = 0.f; wp[3] = 0.f;
            wp[4] = __int_as_float(node);
        }
        for (int k = 0; k < cpad; k += 4) {
            const float* wpA = wbuf + (k + half) * 5;
            const float* wpB = wpA + 10;
            int srcA = __float_as_int(wpA[4]);
            int srcB = __float_as_int(wpB[4]);
            float wgtA = wpA[head8];
            float wgtB = wpB[head8];
            short8 hvA = *(const short8*)(hbase + (size_t)srcA * F1);
            short8 hvB = *(const short8*)(hbase + (size_t)srcB * F1);
            acc[0] += wgtA * bf2f((unsigned short)hvA[0]);
            acc[1] += wgtA * bf2f((unsigned short)hvA[1]);
            acc[2] += wgtA * bf2f((unsigned short)hvA[2]);
            acc[3] += wgtA * bf2f((unsigned short)hvA[3]);
            acc[4] += wgtA * bf2f((unsigned short)hvA[4]);
            acc[5] += wgtA * bf2f((unsigned short)hvA[5]);
            acc[6] += wgtA * bf2f((unsigned short)hvA[6]);
            acc[7] += wgtA * bf2f((unsigned short)hvA[7]);
            acc[0] += wgtB * bf2f((unsigned short)hvB[0]);
            acc[1] += wgtB * bf2f((unsigned short)hvB[1]);
            acc[2] += wgtB * bf2f((unsigned short)hvB[2]);
            acc[3] += wgtB * bf2f((unsigned short)hvB[3]);
            acc[4] += wgtB * bf2f((unsigned short)hvB[4]);
            acc[5] += wgtB * bf2f((unsigned short)hvB[5]);
            acc[6] += wgtB * bf2f((unsigned short)hvB[6]);
            acc[7] += wgtB * bf2f((unsigned short)hvB[7]);
        }
    }
    for (int u = 0; u < 8; ++u) acc[u] += __shfl_xor(acc[u], 32);
    for (int off = 32; off; off >>= 1) {
        den0 += __shfl_xor(den0, off);
        den1 += __shfl_xor(den1, off);
        den2 += __shfl_xor(den2, off);
        den3 += __shfl_xor(den3, off);
    }
    if (half == 0) {
        float den = (head8 == 0) ? den0 : (head8 == 1) ? den1 : (head8 == 2) ? den2 : den3;
        float inv = 1.f / den;
        int j = lp * 8;
        float4 Sv0 = *(const float4*)(S + j);
        float4 Sv1 = *(const float4*)(S + j + 4);
        float4 Tv0 = *(const float4*)(T + j);
        float4 Tv1 = *(const float4*)(T + j + 4);
        short8 o;
        o[0] = (short)f2bf(fmaxf(acc[0] * inv * Sv0.x + Tv0.x, 0.f));
        o[1] = (short)f2bf(fmaxf(acc[1] * inv * Sv0.y + Tv0.y, 0.f));
        o[2] = (short)f2bf(fmaxf(acc[2] * inv * Sv0.z + Tv0.z, 0.f));
        o[3] = (short)f2bf(fmaxf(acc[3] * inv * Sv0.w + Tv0.w, 0.f));
        o[4] = (short)f2bf(fmaxf(acc[4] * inv * Sv1.x + Tv1.x, 0.f));
        o[5] = (short)f2bf(fmaxf(acc[5] * inv * Sv1.y + Tv1.y, 0.f));
        o[6] = (short)f2bf(fmaxf(acc[6] * inv * Sv1.z + Tv1.z, 0.f));
        o[7] = (short)f2bf(fmaxf(acc[7] * inv * Sv1.w + Tv1.w, 0.f));
        *(short8*)(out + (size_t)node * F1 + j) = o;
    }
}

// ---------------- layer-3 GEMM via MFMA (W3 hi/lo split) + fused s3/d3 ----------------
__global__ __launch_bounds__(256) void gemm3_mfma(const unsigned short* __restrict__ A,
                                                  const unsigned short* __restrict__ W3h,
                                                  const unsigned short* __restrict__ W3l,
                                                  const float* __restrict__ as3, const float* __restrict__ ad3,
                                                  float* __restrict__ h3, float* __restrict__ s3,
                                                  float* __restrict__ d3, int M) {
    int tid = threadIdx.x, lane = tid & 63, w = tid >> 6;
    int mBase = blockIdx.x * 64 + w * 16;
    int lm = lane & 15, q = lane >> 4;
    int row = mBase + lm;
    int rc = (row < M) ? row : (M - 1);
    const unsigned short* pA = A + (size_t)rc * 256 + q * 8;
    const unsigned short* pH = W3h + lm * 256 + q * 8;
    const unsigned short* pL = W3l + lm * 256 + q * 8;
    float4v acc = (float4v){0.f, 0.f, 0.f, 0.f};
    #pragma unroll
    for (int s = 0; s < 8; ++s) {
        short8 a  = *(const short8*)(pA + s * 32);
        short8 bh = *(const short8*)(pH + s * 32);
        short8 bl = *(const short8*)(pL + s * 32);
        acc = __builtin_amdgcn_mfma_f32_16x16x32_bf16(a, bh, acc, 0, 0, 0);
        acc = __builtin_amdgcn_mfma_f32_16x16x32_bf16(a, bl, acc, 0, 0, 0);
    }
    float a_s = as3[lm], a_d = ad3[lm];
    for (int r = 0; r < 4; ++r) {
        int rw = mBase + q * 4 + r;
        if (rw < M) h3[(size_t)rw * 16 + lm] = acc[r];
        float sp = acc[r] * a_s, dp = acc[r] * a_d;
        for (int off = 1; off < 16; off <<= 1) {
            sp += __shfl_xor(sp, off);
            dp += __shfl_xor(dp, off);
        }
        if (lm == 0 && rw < M) { s3[rw] = sp; d3[rw] = dp; }
    }
}

// ---------------- layer-3 aggregation: staged weights, 2 loads/iter -> d_out ----------------
__global__ __launch_bounds__(256) void agg3(const float* __restrict__ h3, const float* __restrict__ s3,
                                            const float* __restrict__ d3, const int* __restrict__ rowptr,
                                            const int* __restrict__ csr, const float* __restrict__ b3,
                                            float* __restrict__ out) {
    __shared__ float wls[4][64 * 2];   // per-wave: 64 edges x {w, src}
    int lane = threadIdx.x & 63;
    int wv = threadIdx.x >> 6;
    int node = blockIdx.x * 4 + wv;
    if (node >= NN) return;
    int r0 = rowptr[node], r1 = rowptr[node + 1];
    float dv = d3[node];
    float* wbuf = &wls[wv][0];
    int c = lane & 15, g = lane >> 4;
    float acc = 0.f, den = 0.f;
    for (int base = r0; base < r1; base += 64) {
        int cnt = min(64, r1 - base);
        int cpad = (cnt + 7) & ~7;
        if (lane < cnt) {
            int src = csr[base + lane];
            float w = __expf(lrelu(s3[src] + dv));
            den += w;
            wbuf[lane * 2] = w;
            wbuf[lane * 2 + 1] = __int_as_float(src);
        } else if (lane < cpad) {
            wbuf[lane * 2] = 0.f;
            wbuf[lane * 2 + 1] = __int_as_float(node);
        }
        for (int k = 0; k < cpad; k += 8) {
            const float* wpA = wbuf + (k + g) * 2;
            const float* wpB = wpA + 8;
            float wA = wpA[0]; int sA = __float_as_int(wpA[1]);
            float wB = wpB[0]; int sB = __float_as_int(wpB[1]);
            float hA = h3[(size_t)sA * 16 + c];
            float hB = h3[(size_t)sB * 16 + c];
            acc += wA * hA;
            acc += wB * hB;
        }
    }
    acc += __shfl_xor(acc, 16); acc += __shfl_xor(acc, 32);
    for (int off = 32; off; off >>= 1) den += __shfl_xor(den, off);
    if (lane < 16) out[(size_t)node * 16 + lane] = acc / den + b3[lane];
}

// ---------------- host ----------------
extern "C" void kernel_launch(void* const* d_in, const int* in_sizes, int n_in,
                              void* d_out, int out_size, void* d_ws, size_t ws_size,
                              hipStream_t stream) {
    const float* x   = (const float*)d_in[0];
    const int*   ei  = (const int*)d_in[1];
    const float* W1  = (const float*)d_in[2];
    const float* as1 = (const float*)d_in[3];
    const float* ad1 = (const float*)d_in[4];
    const float* b1  = (const float*)d_in[5];
    const float* g1  = (const float*)d_in[6];
    const float* be1 = (const float*)d_in[7];
    const float* m1  = (const float*)d_in[8];
    const float* v1  = (const float*)d_in[9];
    const float* W2  = (const float*)d_in[10];
    const float* as2 = (const float*)d_in[11];
    const float* ad2 = (const float*)d_in[12];
    const float* b2  = (const float*)d_in[13];
    const float* g2  = (const float*)d_in[14];
    const float* be2 = (const float*)d_in[15];
    const float* m2  = (const float*)d_in[16];
    const float* v2  = (const float*)d_in[17];
    const float* W3  = (const float*)d_in[18];
    const float* as3 = (const float*)d_in[19];
    const float* ad3 = (const float*)d_in[20];
    const float* b3  = (const float*)d_in[21];

    char* w = (char*)d_ws;
    size_t off = 0;
    auto alloc = [&](size_t bytes) -> void* {
        off = (off + 255) & ~(size_t)255;
        void* p = w + off;
        off += bytes;
        return p;
    };
    unsigned short* xb    = (unsigned short*)alloc((size_t)NN * 128 * 2);
    unsigned short* W1t   = (unsigned short*)alloc(256 * 128 * 2);
    unsigned short* W2t   = (unsigned short*)alloc(256 * 256 * 2);
    unsigned short* W3h   = (unsigned short*)alloc(16 * 256 * 2);
    unsigned short* W3l   = (unsigned short*)alloc(16 * 256 * 2);
    unsigned char*  Abuf8 = (unsigned char*)alloc((size_t)NN * F1);      // h1 fp8
    unsigned short* Abuf  = (unsigned short*)alloc((size_t)NN * F1 * 2); // h2 bf16
    unsigned short* Bbuf  = (unsigned short*)alloc((size_t)NN * F1 * 2); // out1 / out2
    float* h3    = (float*)alloc((size_t)NN * 16 * 4);
    float* s_arr = (float*)alloc((size_t)NN * 4 * 4);
    float* d_arr = (float*)alloc((size_t)NN * 4 * 4);
    float* s3    = (float*)alloc((size_t)NN * 4);
    float* d3    = (float*)alloc((size_t)NN * 4);
    int* counts  = (int*)alloc((size_t)NN * 4);
    int* rowptr  = (int*)alloc((size_t)(NN + 1) * 4);
    int* rank    = (int*)alloc((size_t)ET * 4);
    int* csr     = (int*)alloc((size_t)ET * 4);
    int* bsum    = (int*)alloc(256 * 4);
    float* S1 = (float*)alloc(F1 * 4);
    float* T1 = (float*)alloc(F1 * 4);
    float* S2 = (float*)alloc(F1 * 4);
    float* T2 = (float*)alloc(F1 * 4);
    float* outp = (float*)d_out;

    int nb_scan = (NN + 255) / 256;        // 196
    int nb_edge = (ET + 255) / 256;        // 3321

    hipMemsetAsync(counts, 0, (size_t)NN * 4, stream);
    prep_all<<<9973, 256, 0, stream>>>(x, xb, ei, counts, rank,
                                       W1, W1t, W2, W2t, W3, W3h, W3l,
                                       b1, g1, be1, m1, v1, S1, T1,
                                       b2, g2, be2, m2, v2, S2, T2);
    scan_a<<<nb_scan, 256, 0, stream>>>(counts, rowptr, bsum);
    scan_bc<<<nb_scan, 256, 0, stream>>>(rowptr, bsum, nb_scan);
    edge_place<<<nb_edge, 256, 0, stream>>>(ei, rowptr, rank, csr);

    dim3 ggrid((NN + 127) / 128, 2);
    int agrid = (NN + 3) / 4;

    // layer 1 (C in fp8: h1 only feeds agg1 messages)
    gemm_lds<128, true><<<ggrid, 256, 0, stream>>>(xb, W1t, Abuf8, as1, ad1, s_arr, d_arr, NN);
    agg12_f8<<<agrid, 256, 0, stream>>>(Abuf8, s_arr, d_arr, rowptr, csr, S1, T1, Bbuf);

    // layer 2 (bf16 throughout)
    gemm_lds<256, false><<<ggrid, 256, 0, stream>>>(Bbuf, W2t, Abuf, as2, ad2, s_arr, d_arr, NN);
    agg12<<<agrid, 256, 0, stream>>>(Abuf, s_arr, d_arr, rowptr, csr, S2, T2, Bbuf);

    // layer 3
    gemm3_mfma<<<(NN + 63) / 64, 256, 0, stream>>>(Bbuf, W3h, W3l, as3, ad3, h3, s3, d3, NN);
    agg3<<<agrid, 256, 0, stream>>>(h3, s3, d3, rowptr, csr, b3, outp);
}